// Round 11
// baseline (3320.584 us; speedup 1.0000x reference)
//
#include <hip/hip_runtime.h>
#include <hip/hip_bf16.h>
#include <math.h>

// ---------------- types ----------------
typedef __attribute__((ext_vector_type(4))) float f32x4;
typedef __attribute__((ext_vector_type(8))) short short8;

#define NTOK 25088   // B*H*W = 8*56*56
#define DD   640

__device__ __forceinline__ void gload_lds16(const void* g, void* l) {
    __builtin_amdgcn_global_load_lds((const __attribute__((address_space(1))) void*)g,
                                     (__attribute__((address_space(3))) void*)l,
                                     16, 0, 0);
}

// exact rewrite of tanh-gelu: 0.5t(1+tanh(v)) = t * sigmoid(2v)
__device__ __forceinline__ float gelu_f(float t) {
    float u = 1.5957691216057308f * (t + 0.044715f * t * t * t);
    float e = __builtin_amdgcn_exp2f(u * -1.4426950408889634f);   // exp(-u)
    return t / (1.f + e);
}

// ---------------- constants init: NSCT filters + padded biases ----------------
__global__ void init_consts(float* __restrict__ filt, float* __restrict__ linbp,
                            const float* __restrict__ lin_b, float* __restrict__ convbp,
                            const float* __restrict__ conv_b) {
    int t = threadIdx.x;
    if (t == 0) {
        float g[25]; float s = 0.f;
        for (int i = 0; i < 5; i++) for (int j = 0; j < 5; j++) {
            float yy = (float)(i - 2), xx = (float)(j - 2);
            float v = expf(-(xx*xx + yy*yy) * 0.25f);
            g[i*5+j] = v; s += v;
        }
        for (int i = 0; i < 25; i++) { g[i] /= s; filt[i] = g[i]; }
        for (int k = 0; k < 8; k++) {
            float th = (float)k * 3.14159265358979323846f / 8.f;
            float ct = cosf(th), st = sinf(th);
            float d[25]; float mean = 0.f;
            for (int i = 0; i < 5; i++) for (int j = 0; j < 5; j++) {
                float yy = (float)(i - 2), xx = (float)(j - 2);
                d[i*5+j] = (ct*xx + st*yy) * g[i*5+j];
                mean += d[i*5+j];
            }
            mean *= (1.f/25.f);
            float ss = 0.f;
            for (int i = 0; i < 25; i++) { d[i] -= mean; ss += d[i]*d[i]; }
            ss = sqrtf(ss);
            for (int i = 0; i < 25; i++) filt[(k+1)*25 + i] = d[i] / ss;
        }
    }
    for (int i = t; i < 640; i += 256) linbp[i]  = (i < 576) ? lin_b[i]  : 0.f;
    for (int i = t; i < 128; i += 256) convbp[i] = (i < 64)  ? conv_b[i] : 0.f;
}

// ---------------- weight transpose+cast: dst[n][k] = bf16(src[k][n]), zero-pad n>=Nsrc ----------------
__global__ __launch_bounds__(256)
void wtrans_kernel(const float* __restrict__ src, __hip_bfloat16* __restrict__ dst,
                   int K, int Nsrc) {
    __shared__ float tile[32][33];
    const int n0 = blockIdx.x * 32;
    const int k0 = blockIdx.y * 32;
    const int tx = threadIdx.x, ty = threadIdx.y;
    #pragma unroll
    for (int r = ty; r < 32; r += 8) {
        int k = k0 + r, n = n0 + tx;
        tile[r][tx] = (n < Nsrc) ? src[(long)k * Nsrc + n] : 0.f;
    }
    __syncthreads();
    #pragma unroll
    for (int r = ty; r < 32; r += 8) {
        int n = n0 + r, k = k0 + tx;
        dst[(long)n * K + k] = __float2bfloat16(tile[tx][r]);
    }
}

__global__ void wcast_kernel(const float* __restrict__ src, __hip_bfloat16* __restrict__ dst,
                             int count, int total) {
    int i = blockIdx.x * 256 + threadIdx.x;
    if (i < total) dst[i] = __float2bfloat16(i < count ? src[i] : 0.f);
}

// ---------------- prep: relu + 9-band NSCT conv + concat -> x3 [NTOK][640] ----------------
__global__ __launch_bounds__(256)
void prep_kernel(const float* __restrict__ x, const float* __restrict__ filt,
                 float* __restrict__ x3) {
    __shared__ float sf[225];
    for (int i = threadIdx.x; i < 225; i += 256) sf[i] = filt[i];
    __syncthreads();
    int id = blockIdx.x * 256 + threadIdx.x;   // B*H*W*C
    int c = id & 63;
    int pix = id >> 6;
    int w = pix % 56, h = (pix / 56) % 56, b = pix / 3136;
    const float* xp = x + (long)(b * 64 + c) * 3136;
    float nb[25];
    #pragma unroll
    for (int dy = 0; dy < 5; dy++) {
        int hy = h + dy - 2;
        #pragma unroll
        for (int dx = 0; dx < 5; dx++) {
            int wx = w + dx - 2;
            float v = 0.f;
            if (hy >= 0 && hy < 56 && wx >= 0 && wx < 56) v = fmaxf(xp[hy*56 + wx], 0.f);
            nb[dy*5 + dx] = v;
        }
    }
    float* orow = x3 + (long)pix * DD;
    #pragma unroll
    for (int band = 0; band < 9; band++) {
        float a = 0.f;
        #pragma unroll
        for (int t = 0; t < 25; t++) a += nb[t] * sf[band*25 + t];
        orow[band*64 + c] = a;
    }
    orow[576 + c] = nb[12];  // relu(x) center copy
}

// ---------------- LayerNorm (per-token over 640) -> bf16 ----------------
__global__ __launch_bounds__(256)
void ln_kernel(const float* __restrict__ xin, const float* __restrict__ g,
               const float* __restrict__ bt, __hip_bfloat16* __restrict__ out) {
    const int lane = threadIdx.x & 63;
    const long tok = (long)blockIdx.x * 4 + (threadIdx.x >> 6);
    const float* xr = xin + tok * DD;
    float v[10]; float s = 0.f, s2 = 0.f;
    #pragma unroll
    for (int i = 0; i < 10; i++) { float t = xr[lane + (i << 6)]; v[i] = t; s += t; s2 += t*t; }
    #pragma unroll
    for (int o = 32; o > 0; o >>= 1) { s += __shfl_down(s, o); s2 += __shfl_down(s2, o); }
    s = __shfl(s, 0); s2 = __shfl(s2, 0);
    const float mean = s * (1.f/640.f);
    const float var  = s2 * (1.f/640.f) - mean * mean;
    const float inv  = 1.f / sqrtf(var + 1e-5f);
    __hip_bfloat16* orow = out + tok * DD;
    #pragma unroll
    for (int i = 0; i < 10; i++) {
        int c = lane + (i << 6);
        orow[c] = __float2bfloat16((v[i] - mean) * inv * g[c] + bt[c]);
    }
}

// ===== 128x128 GEMM, BK=32, double-buffer, 5 blocks/CU (20 waves/CU) — occupancy lever =====
// C[M,N] = A[M,K](bf16) @ Bt[N,K]^T(bf16); 256 thr = 4 waves (2M x 2N), per-wave 64x64.
// R5..R10 series showed dur is monotone in waves/CU (8->172-179us, 12->154us); no pipe is
// saturated (LDS-read 32%, MFMA 23%, VALU 43%) -> latency-bound. LDS: 2 x 16KB = 32KB ->
// 5 blocks/CU. Minimal T3 2-phase loop: vmcnt(0) at top waits exactly own tile-t loads
// (only ones in flight), ONE barrier per K-tile, STAGE(t+1) after barrier overlaps compute.
// Swizzle: 16B slot ^= (row>>1)&3 on global source + LDS read (rule #21, 0 conflicts).
// mode: 0 = normal stores; 1 = NCHW scatter store (final conv, fuses unpack).
__global__ __launch_bounds__(256, 5)
void gemm128_kernel(const __hip_bfloat16* __restrict__ A,
                    const __hip_bfloat16* __restrict__ Bt,
                    const float* __restrict__ bias,
                    const float* __restrict__ resid,
                    float* __restrict__ Cf,
                    __hip_bfloat16* __restrict__ Cb,
                    int K, int ldc, int ncf, int ldb, int col_off, int ncb,
                    int act_gelu, int nvalid, int mode) {
    extern __shared__ __align__(16) char smraw[];   // 2 x 16384B: [A 8192 | B 8192]

    const int tid  = threadIdx.x;
    const int lane = tid & 63;
    const int wv   = tid >> 6;
    const int wr   = wv >> 1;          // 0..1  (M half: 64 rows)
    const int wc   = wv & 1;           // 0..1  (N half: 64 cols)

    // ---- bijective XCD-aware block remap (m204) ----
    const int gx   = gridDim.x;
    const int nwg  = gx * gridDim.y;
    const int orig = blockIdx.y * gx + blockIdx.x;
    const int qq = nwg >> 3, rr = nwg & 7;
    const int xcd = orig & 7, lid = orig >> 3;
    const int wg = (xcd < rr ? xcd * (qq + 1) : rr * (qq + 1) + (xcd - rr) * qq) + lid;
    const long m0 = (long)(wg / gx) * 128;
    const long n0 = (long)(wg % gx) * 128;

    const bool wact = ((int)n0 + (wc << 6)) < nvalid;

    f32x4 acc[4][4];
    #pragma unroll
    for (int i = 0; i < 4; i++)
        #pragma unroll
        for (int j = 0; j < 4; j++) acc[i][j] = (f32x4){0.f, 0.f, 0.f, 0.f};

    // staging: per K-tile(32) each matrix tile is 8KB = 2 x (256 thr x 16B)
    // thread -> row r0 = tid>>2 (and r0+64), 16B slot sl = tid&3,
    // inverse-swizzled source slot ssl = sl ^ ((r0>>1)&3)  (same for r0+64)
    const int r0  = tid >> 2;
    const int sl  = tid & 3;
    const int ssl = sl ^ ((r0 >> 1) & 3);
    const __hip_bfloat16* Agb = A  + (m0 + r0) * (long)K + (ssl << 3);
    const __hip_bfloat16* Bgb = Bt + (n0 + r0) * (long)K + (ssl << 3);
    char* dA = smraw + r0 * 64 + sl * 16;            // linear LDS dest
    char* dB = dA + 8192;

    const int frow = lane & 15;
    const int fks  = lane >> 4;                      // 0..3 (k-slot within K=32)
    const int colA = (fks ^ ((frow >> 1) & 3)) << 4; // swizzled 16B slot -> byte offset

    auto STAGE = [&](int b, int kt) {
        const long ko = (long)kt << 5;
        gload_lds16(Agb + ko,                dA + b * 16384);
        gload_lds16(Agb + 64 * (long)K + ko, dA + b * 16384 + 4096);
        gload_lds16(Bgb + ko,                dB + b * 16384);
        gload_lds16(Bgb + 64 * (long)K + ko, dB + b * 16384 + 4096);
    };

    const int nt = K >> 5;                           // >= 20 at all call sites
    STAGE(0, 0);
    for (int t = 0; t < nt; ++t) {
        asm volatile("s_waitcnt vmcnt(0)" ::: "memory");   // own tile-t loads (all in flight)
        __builtin_amdgcn_s_barrier();        // everyone's tile-t landed; compute(t-1) done
        __builtin_amdgcn_sched_barrier(0);
        if (t + 1 < nt) STAGE((t + 1) & 1, t + 1);   // overlaps compute(t)
        if (wact) {
            const char* pA = smraw + (t & 1) * 16384;
            const char* pB = pA + 8192;
            short8 af[4], bfr[4];
            #pragma unroll
            for (int mi = 0; mi < 4; ++mi)
                af[mi] = *(const short8*)(pA + ((wr << 6) + (mi << 4) + frow) * 64 + colA);
            #pragma unroll
            for (int nj = 0; nj < 4; ++nj)
                bfr[nj] = *(const short8*)(pB + ((wc << 6) + (nj << 4) + frow) * 64 + colA);
            __builtin_amdgcn_s_setprio(1);
            #pragma unroll
            for (int mi = 0; mi < 4; ++mi)
                #pragma unroll
                for (int nj = 0; nj < 4; ++nj)       // SWAPPED: D rows <- N, cols <- M
                    acc[mi][nj] = __builtin_amdgcn_mfma_f32_16x16x32_bf16(
                        bfr[nj], af[mi], acc[mi][nj], 0, 0, 0);
            __builtin_amdgcn_s_setprio(0);
        }
    }

    if (!wact) return;
    // epilogue: lane holds m = frow (fixed), n = base + fks*4 + r  (4 consecutive cols)
    const int nlim = (ncf > ncb) ? ncf : ncb;
    #pragma unroll
    for (int mi = 0; mi < 4; ++mi) {
        const long row = m0 + (wr << 6) + (mi << 4) + frow;
        #pragma unroll
        for (int nj = 0; nj < 4; ++nj) {
            const int n = (int)n0 + (wc << 6) + (nj << 4) + (fks << 2);
            if (n >= nlim) continue;
            f32x4 v = acc[mi][nj];
            if (bias) {
                const f32x4 bv = *(const f32x4*)&bias[n];
                v += bv;
            }
            if (act_gelu) {
                v[0] = gelu_f(v[0]); v[1] = gelu_f(v[1]); v[2] = gelu_f(v[2]); v[3] = gelu_f(v[3]);
            }
            if (mode == 1) {
                // NCHW scatter: out[(b*64 + n+r)*3136 + pos], row = b*3136 + pos
                const int b = (int)(row / 3136), pos = (int)(row % 3136);
                #pragma unroll
                for (int r = 0; r < 4; ++r)
                    Cf[(long)(b * 64 + n + r) * 3136 + pos] = v[r];
                continue;
            }
            if (resid && n < ncf) v += *(const f32x4*)&resid[row * (long)ldc + n];
            if (Cf && n < ncf) *(f32x4*)&Cf[row * (long)ldc + n] = v;
            if (Cb && n < ncb) {
                short4 p;
                p.x = (short)__bfloat16_as_short(__float2bfloat16(v[0]));
                p.y = (short)__bfloat16_as_short(__float2bfloat16(v[1]));
                p.z = (short)__bfloat16_as_short(__float2bfloat16(v[2]));
                p.w = (short)__bfloat16_as_short(__float2bfloat16(v[3]));
                *(short4*)&Cb[row * (long)ldb + col_off + n] = p;
            }
        }
    }
}

// ---------------- window attention (per window-head, fp32 in LDS) ----------------
__global__ __launch_bounds__(256)
void attn_kernel(const __hip_bfloat16* __restrict__ qkv, __hip_bfloat16* __restrict__ o,
                 int shift) {
    __shared__ __align__(16) float qT[80][52];
    __shared__ __align__(16) float kT[80][52];
    __shared__ __align__(16) float vs[50][80];
    __shared__ __align__(16) float ss[49][52];
    __shared__ int toks[49];
    __shared__ int rid[49];

    const int tid = threadIdx.x;
    const int win = blockIdx.x >> 3;
    const int hd  = blockIdx.x & 7;
    const int b   = win >> 6;
    const int wh  = (win >> 3) & 7;
    const int ww  = win & 7;

    if (tid < 49) {
        int i = tid / 7, j = tid % 7;
        int ph = wh * 7 + i, pw = ww * 7 + j;
        int sh = ph + shift; if (sh >= 56) sh -= 56;
        int sw = pw + shift; if (sw >= 56) sw -= 56;
        toks[tid] = (b * 56 + sh) * 56 + sw;
        int rh = (ph < 49) ? 0 : ((ph < 53) ? 1 : 2);
        int rw = (pw < 49) ? 0 : ((pw < 53) ? 1 : 2);
        rid[tid] = rh * 3 + rw;
    }
    for (int i = tid; i < 80 * 3; i += 256) {
        int d = i / 3, cc = 49 + (i % 3);
        qT[d][cc] = 0.f; kT[d][cc] = 0.f;
    }
    __syncthreads();
    for (int idx = tid; idx < 49 * 80; idx += 256) {
        int t = idx / 80, d = idx % 80;
        long base = (long)toks[t] * 1920 + hd * 80 + d;
        qT[d][t] = __bfloat162float(qkv[base]);
        kT[d][t] = __bfloat162float(qkv[base + 640]);
        vs[t][d] = __bfloat162float(qkv[base + 1280]);
    }
    __syncthreads();
    const float scale = 0.11180339887498948f;
    for (int p = tid; p < 49 * 13; p += 256) {
        int t = p / 13, j0 = (p % 13) * 4;
        float4 a = {0.f, 0.f, 0.f, 0.f};
        #pragma unroll
        for (int d = 0; d < 80; d++) {
            float qv = qT[d][t];
            float4 kv = *(const float4*)&kT[d][j0];
            a.x += qv * kv.x; a.y += qv * kv.y; a.z += qv * kv.z; a.w += qv * kv.w;
        }
        a.x *= scale; a.y *= scale; a.z *= scale; a.w *= scale;
        *(float4*)&ss[t][j0] = a;
    }
    __syncthreads();
    // parallel softmax: 4 lanes per row (196 threads), shfl_xor reduce within 4-lane group
    if (tid < 196) {
        const int r = tid >> 2, sub = tid & 3;
        const int j0 = sub * 13;
        const int j1 = (sub == 3) ? 10 : 13;
        const int myr = rid[r];
        float mx = -1e30f;
        for (int i = 0; i < j1; i++) {
            float v = ss[r][j0 + i];
            if (shift && rid[j0 + i] != myr) v = -1e9f;
            ss[r][j0 + i] = v;
            mx = fmaxf(mx, v);
        }
        mx = fmaxf(mx, __shfl_xor(mx, 1));
        mx = fmaxf(mx, __shfl_xor(mx, 2));
        float sum = 0.f;
        for (int i = 0; i < j1; i++) {
            float e = __expf(ss[r][j0 + i] - mx);
            ss[r][j0 + i] = e;
            sum += e;
        }
        sum += __shfl_xor(sum, 1);
        sum += __shfl_xor(sum, 2);
        const float inv = 1.f / sum;
        for (int i = 0; i < j1; i++) ss[r][j0 + i] *= inv;
    }
    __syncthreads();
    for (int p = tid; p < 49 * 20; p += 256) {
        int t = p / 20, dv = (p % 20) * 4;
        float4 a = {0.f, 0.f, 0.f, 0.f};
        for (int j = 0; j < 49; j++) {
            float w = ss[t][j];
            float4 vv = *(const float4*)&vs[j][dv];
            a.x += w * vv.x; a.y += w * vv.y; a.z += w * vv.z; a.w += w * vv.w;
        }
        long base = (long)toks[t] * DD + hd * 80 + dv;
        o[base + 0] = __float2bfloat16(a.x);
        o[base + 1] = __float2bfloat16(a.y);
        o[base + 2] = __float2bfloat16(a.z);
        o[base + 3] = __float2bfloat16(a.w);
    }
}

// ---------------- inverse NSCT: 4 channels per thread, float4 loads ----------------
__global__ __launch_bounds__(256)
void ict_kernel(const float* __restrict__ y, const float* __restrict__ filt,
                __hip_bfloat16* __restrict__ ayc) {
    __shared__ float sf[225];
    for (int i = threadIdx.x; i < 225; i += 256) sf[i] = filt[i];
    __syncthreads();
    int id = blockIdx.x * 256 + threadIdx.x;   // NTOK * 16
    int c4 = (id & 15) << 2;
    int pix = id >> 4;
    int w = pix % 56, h = (pix / 56) % 56, b = pix / 3136;
    float4 a = {0.f, 0.f, 0.f, 0.f};
    #pragma unroll
    for (int dy = 0; dy < 5; dy++) {
        int hy = h + dy - 2;
        if (hy < 0 || hy >= 56) continue;
        #pragma unroll
        for (int dx = 0; dx < 5; dx++) {
            int wx = w + dx - 2;
            if (wx < 0 || wx >= 56) continue;
            const float* yr = y + ((long)(b * 56 + hy) * 56 + wx) * DD + c4;
            #pragma unroll
            for (int band = 0; band < 9; band++) {
                const float f = sf[band*25 + dy*5 + dx];
                const float4 vv = *(const float4*)&yr[band * 64];
                a.x += vv.x * f; a.y += vv.y * f; a.z += vv.z * f; a.w += vv.w * f;
            }
        }
    }
    short4 p;
    p.x = (short)__bfloat16_as_short(__float2bfloat16(a.x));
    p.y = (short)__bfloat16_as_short(__float2bfloat16(a.y));
    p.z = (short)__bfloat16_as_short(__float2bfloat16(a.z));
    p.w = (short)__bfloat16_as_short(__float2bfloat16(a.w));
    *(short4*)&ayc[(long)pix * DD + c4] = p;
}

// ---------------- host ----------------
extern "C" void kernel_launch(void* const* d_in, const int* in_sizes, int n_in,
                              void* d_out, int out_size, void* d_ws, size_t ws_size,
                              hipStream_t stream) {
    (void)in_sizes; (void)n_in; (void)out_size; (void)ws_size;
    const float* x      = (const float*)d_in[0];
    const float* ln1_g  = (const float*)d_in[1];
    const float* ln1_b  = (const float*)d_in[2];
    const float* qkv_w  = (const float*)d_in[3];
    const float* qkv_b  = (const float*)d_in[4];
    const float* proj_w = (const float*)d_in[5];
    const float* proj_b = (const float*)d_in[6];
    const float* ln2_g  = (const float*)d_in[7];
    const float* ln2_b  = (const float*)d_in[8];
    const float* fc1_w  = (const float*)d_in[9];
    const float* fc1_b  = (const float*)d_in[10];
    const float* fc2_w  = (const float*)d_in[11];
    const float* fc2_b  = (const float*)d_in[12];
    const float* lin_w  = (const float*)d_in[13];
    const float* lin_b  = (const float*)d_in[14];
    const float* conv_w = (const float*)d_in[15];
    const float* conv_b = (const float*)d_in[16];

    char* ws = (char*)d_ws;
    size_t off = 0;
    auto alloc = [&](size_t bytes) -> void* {
        void* p = ws + off;
        off += (bytes + 255) & ~(size_t)255;
        return p;
    };
    float* filt   = (float*)alloc(225 * 4);
    float* linbp  = (float*)alloc(640 * 4);
    float* convbp = (float*)alloc(128 * 4);
    __hip_bfloat16* qkvWt[2], *projWt[2], *fc1Wt[2], *fc2Wt[2];
    for (int i = 0; i < 2; i++) qkvWt[i] = (__hip_bfloat16*)alloc(1920L * 640 * 2);
    for (int i = 0; i < 2; i++) projWt[i] = (__hip_bfloat16*)alloc(640L * 640 * 2);
    for (int i = 0; i < 2; i++) fc1Wt[i] = (__hip_bfloat16*)alloc(2560L * 640 * 2);
    for (int i = 0; i < 2; i++) fc2Wt[i] = (__hip_bfloat16*)alloc(640L * 2560 * 2);
    __hip_bfloat16* linWt  = (__hip_bfloat16*)alloc(640L * 640 * 2);   // N padded 576->640
    __hip_bfloat16* convWt = (__hip_bfloat16*)alloc(128L * 640 * 2);   // N padded 64->128
    float* x3 = (float*)alloc((long)NTOK * DD * 4);
    __hip_bfloat16* bufA = (__hip_bfloat16*)alloc((long)NTOK * DD * 2);
    char* bufB = (char*)alloc((long)NTOK * 2560 * 2);
    __hip_bfloat16* qkv = (__hip_bfloat16*)bufB;
    __hip_bfloat16* h2  = (__hip_bfloat16*)bufB;
    float* ybuf = (float*)bufB;
    __hip_bfloat16* ayc = (__hip_bfloat16*)(bufB + (long)NTOK * DD * 4);

    hipFuncSetAttribute((const void*)gemm128_kernel,
                        hipFuncAttributeMaxDynamicSharedMemorySize, 32768);

    dim3 tb(32, 8);
    init_consts<<<1, 256, 0, stream>>>(filt, linbp, lin_b, convbp, conv_b);
    for (int i = 0; i < 2; i++) {
        wtrans_kernel<<<dim3(60, 20), tb, 0, stream>>>(qkv_w + (long)i*640*1920, qkvWt[i], 640, 1920);
        wtrans_kernel<<<dim3(20, 20), tb, 0, stream>>>(proj_w + (long)i*640*640,  projWt[i], 640, 640);
        wtrans_kernel<<<dim3(80, 20), tb, 0, stream>>>(fc1_w + (long)i*640*2560, fc1Wt[i], 640, 2560);
        wtrans_kernel<<<dim3(20, 80), tb, 0, stream>>>(fc2_w + (long)i*2560*640, fc2Wt[i], 2560, 640);
    }
    wtrans_kernel<<<dim3(20, 20), tb, 0, stream>>>(lin_w, linWt, 640, 576);
    wcast_kernel<<<320, 256, 0, stream>>>(conv_w, convWt, 64 * 640, 128 * 640);

    prep_kernel<<<6272, 256, 0, stream>>>(x, filt, x3);

    for (int i = 0; i < 2; i++) {
        int shift = i ? 3 : 0;
        ln_kernel<<<6272, 256, 0, stream>>>(x3, ln1_g + i*640, ln1_b + i*640, bufA);
        // qkv: N=1920 exact (15 col-tiles), bf16 out
        gemm128_kernel<<<dim3(15, 196), 256, 32768, stream>>>(bufA, qkvWt[i], qkv_b + i*1920,
            nullptr, nullptr, qkv, 640, 0, 0, 1920, 0, 1920, 0, 1920, 0);
        attn_kernel<<<4096, 256, 0, stream>>>(qkv, bufA, shift);
        // proj: N=640 exact, fp32 out + resid into x3
        gemm128_kernel<<<dim3(5, 196), 256, 32768, stream>>>(bufA, projWt[i], proj_b + i*640,
            x3, x3, nullptr, 640, 640, 640, 0, 0, 0, 0, 640, 0);
        ln_kernel<<<6272, 256, 0, stream>>>(x3, ln2_g + i*640, ln2_b + i*640, bufA);
        // fc1: N=2560 exact, gelu, bf16 out
        gemm128_kernel<<<dim3(20, 196), 256, 32768, stream>>>(bufA, fc1Wt[i], fc1_b + i*2560,
            nullptr, nullptr, h2, 640, 0, 0, 2560, 0, 2560, 1, 2560, 0);
        // fc2: N=640 exact, K=2560, resid into x3; last iter also mirrors bf16 into bufA
        gemm128_kernel<<<dim3(5, 196), 256, 32768, stream>>>(h2, fc2Wt[i], fc2_b + i*640,
            x3, x3, (i == 1) ? bufA : nullptr, 2560, 640, 640, 640, 0, (i == 1) ? 640 : 0, 0, 640, 0);
    }
    // lin: fp32 out (640 cols, 576 valid) + bf16 mirror into ayc cols [64,640)
    gemm128_kernel<<<dim3(5, 196), 256, 32768, stream>>>(bufA, linWt, linbp,
        nullptr, ybuf, ayc, 640, 640, 640, 640, 64, 576, 0, 576, 0);
    ict_kernel<<<1568, 256, 0, stream>>>(ybuf, filt, ayc);
    // conv: N=128 (64 valid), direct NCHW store into d_out (fuses unpack)
    gemm128_kernel<<<dim3(1, 196), 256, 32768, stream>>>(ayc, convWt, convbp,
        nullptr, (float*)d_out, nullptr, 640, 0, 64, 0, 0, 0, 0, 64, 1);
}

// Round 12
// 1372.027 us; speedup vs baseline: 2.4202x; 2.4202x over previous
//
#include <hip/hip_runtime.h>
#include <hip/hip_bf16.h>
#include <math.h>

// ---------------- types ----------------
typedef __attribute__((ext_vector_type(4))) float f32x4;
typedef __attribute__((ext_vector_type(8))) short short8;

#define NTOK 25088   // B*H*W = 8*56*56
#define DD   640

__device__ __forceinline__ void gload_lds16(const void* g, void* l) {
    __builtin_amdgcn_global_load_lds((const __attribute__((address_space(1))) void*)g,
                                     (__attribute__((address_space(3))) void*)l,
                                     16, 0, 0);
}

// exact rewrite of tanh-gelu: 0.5t(1+tanh(v)) = t * sigmoid(2v)
__device__ __forceinline__ float gelu_f(float t) {
    float u = 1.5957691216057308f * (t + 0.044715f * t * t * t);
    float e = __builtin_amdgcn_exp2f(u * -1.4426950408889634f);   // exp(-u)
    return t / (1.f + e);
}

// ---------------- constants init: NSCT filters + padded biases ----------------
__global__ void init_consts(float* __restrict__ filt, float* __restrict__ linbp,
                            const float* __restrict__ lin_b, float* __restrict__ convbp,
                            const float* __restrict__ conv_b) {
    int t = threadIdx.x;
    if (t == 0) {
        float g[25]; float s = 0.f;
        for (int i = 0; i < 5; i++) for (int j = 0; j < 5; j++) {
            float yy = (float)(i - 2), xx = (float)(j - 2);
            float v = expf(-(xx*xx + yy*yy) * 0.25f);
            g[i*5+j] = v; s += v;
        }
        for (int i = 0; i < 25; i++) { g[i] /= s; filt[i] = g[i]; }
        for (int k = 0; k < 8; k++) {
            float th = (float)k * 3.14159265358979323846f / 8.f;
            float ct = cosf(th), st = sinf(th);
            float d[25]; float mean = 0.f;
            for (int i = 0; i < 5; i++) for (int j = 0; j < 5; j++) {
                float yy = (float)(i - 2), xx = (float)(j - 2);
                d[i*5+j] = (ct*xx + st*yy) * g[i*5+j];
                mean += d[i*5+j];
            }
            mean *= (1.f/25.f);
            float ss = 0.f;
            for (int i = 0; i < 25; i++) { d[i] -= mean; ss += d[i]*d[i]; }
            ss = sqrtf(ss);
            for (int i = 0; i < 25; i++) filt[(k+1)*25 + i] = d[i] / ss;
        }
    }
    for (int i = t; i < 640; i += 256) linbp[i]  = (i < 576) ? lin_b[i]  : 0.f;
    for (int i = t; i < 128; i += 256) convbp[i] = (i < 64)  ? conv_b[i] : 0.f;
}

// ---------------- weight transpose+cast: dst[n][k] = bf16(src[k][n]), zero-pad n>=Nsrc ----------------
__global__ __launch_bounds__(256)
void wtrans_kernel(const float* __restrict__ src, __hip_bfloat16* __restrict__ dst,
                   int K, int Nsrc) {
    __shared__ float tile[32][33];
    const int n0 = blockIdx.x * 32;
    const int k0 = blockIdx.y * 32;
    const int tx = threadIdx.x, ty = threadIdx.y;
    #pragma unroll
    for (int r = ty; r < 32; r += 8) {
        int k = k0 + r, n = n0 + tx;
        tile[r][tx] = (n < Nsrc) ? src[(long)k * Nsrc + n] : 0.f;
    }
    __syncthreads();
    #pragma unroll
    for (int r = ty; r < 32; r += 8) {
        int n = n0 + r, k = k0 + tx;
        dst[(long)n * K + k] = __float2bfloat16(tile[tx][r]);
    }
}

__global__ void wcast_kernel(const float* __restrict__ src, __hip_bfloat16* __restrict__ dst,
                             int count, int total) {
    int i = blockIdx.x * 256 + threadIdx.x;
    if (i < total) dst[i] = __float2bfloat16(i < count ? src[i] : 0.f);
}

// ---------------- prep: relu + 9-band NSCT conv + concat -> x3 [NTOK][640] ----------------
__global__ __launch_bounds__(256)
void prep_kernel(const float* __restrict__ x, const float* __restrict__ filt,
                 float* __restrict__ x3) {
    __shared__ float sf[225];
    for (int i = threadIdx.x; i < 225; i += 256) sf[i] = filt[i];
    __syncthreads();
    int id = blockIdx.x * 256 + threadIdx.x;   // B*H*W*C
    int c = id & 63;
    int pix = id >> 6;
    int w = pix % 56, h = (pix / 56) % 56, b = pix / 3136;
    const float* xp = x + (long)(b * 64 + c) * 3136;
    float nb[25];
    #pragma unroll
    for (int dy = 0; dy < 5; dy++) {
        int hy = h + dy - 2;
        #pragma unroll
        for (int dx = 0; dx < 5; dx++) {
            int wx = w + dx - 2;
            float v = 0.f;
            if (hy >= 0 && hy < 56 && wx >= 0 && wx < 56) v = fmaxf(xp[hy*56 + wx], 0.f);
            nb[dy*5 + dx] = v;
        }
    }
    float* orow = x3 + (long)pix * DD;
    #pragma unroll
    for (int band = 0; band < 9; band++) {
        float a = 0.f;
        #pragma unroll
        for (int t = 0; t < 25; t++) a += nb[t] * sf[band*25 + t];
        orow[band*64 + c] = a;
    }
    orow[576 + c] = nb[12];  // relu(x) center copy
}

// ---------------- LayerNorm (per-token over 640) -> bf16 ----------------
__global__ __launch_bounds__(256)
void ln_kernel(const float* __restrict__ xin, const float* __restrict__ g,
               const float* __restrict__ bt, __hip_bfloat16* __restrict__ out) {
    const int lane = threadIdx.x & 63;
    const long tok = (long)blockIdx.x * 4 + (threadIdx.x >> 6);
    const float* xr = xin + tok * DD;
    float v[10]; float s = 0.f, s2 = 0.f;
    #pragma unroll
    for (int i = 0; i < 10; i++) { float t = xr[lane + (i << 6)]; v[i] = t; s += t; s2 += t*t; }
    #pragma unroll
    for (int o = 32; o > 0; o >>= 1) { s += __shfl_down(s, o); s2 += __shfl_down(s2, o); }
    s = __shfl(s, 0); s2 = __shfl(s2, 0);
    const float mean = s * (1.f/640.f);
    const float var  = s2 * (1.f/640.f) - mean * mean;
    const float inv  = 1.f / sqrtf(var + 1e-5f);
    __hip_bfloat16* orow = out + tok * DD;
    #pragma unroll
    for (int i = 0; i < 10; i++) {
        int c = lane + (i << 6);
        orow[c] = __float2bfloat16((v[i] - mean) * inv * g[c] + bt[c]);
    }
}

// ===== 128x128 GEMM, BK=32, double-buffer 32KB, 4 blocks/CU (16 waves/CU) =====
// C[M,N] = A[M,K](bf16) @ Bt[N,K]^T(bf16); 256 thr = 4 waves (2M x 2N), per-wave 64x64.
// Occupancy curve (measured): 8 waves/CU -> 172-179us, 12 -> 154us; latency-bound regime.
// This kernel needs ~124 unified regs/thread (64 AGPR acc + ~60 VGPR) -> HW cap is
// 4 waves/SIMD. __launch_bounds__(256,3) keeps the compiler budget at 170 (NO SPILL —
// R11's (256,5) forced budget 96 and spilled acc to scratch: WRITE_SIZE 10x, 2.4x slower).
// Runtime occupancy = min(LDS 160/32=5, regs 4) = 4 blocks/CU.
// Loop: one barrier per K-tile; STAGE(t+1) after barrier overlaps compute(t); vmcnt(0)
// at top waits exactly own tile-t loads (issued one iteration earlier).
// Swizzle: 16B slot ^= (row>>1)&3 on global source + LDS read (rule #21, 0 conflicts).
// mode: 0 = normal stores; 1 = NCHW scatter store (final conv, fuses unpack).
__global__ __launch_bounds__(256, 3)
void gemm128_kernel(const __hip_bfloat16* __restrict__ A,
                    const __hip_bfloat16* __restrict__ Bt,
                    const float* __restrict__ bias,
                    const float* __restrict__ resid,
                    float* __restrict__ Cf,
                    __hip_bfloat16* __restrict__ Cb,
                    int K, int ldc, int ncf, int ldb, int col_off, int ncb,
                    int act_gelu, int nvalid, int mode) {
    extern __shared__ __align__(16) char smraw[];   // 2 x 16384B: [A 8192 | B 8192]

    const int tid  = threadIdx.x;
    const int lane = tid & 63;
    const int wv   = tid >> 6;
    const int wr   = wv >> 1;          // 0..1  (M half: 64 rows)
    const int wc   = wv & 1;           // 0..1  (N half: 64 cols)

    // ---- bijective XCD-aware block remap (m204) ----
    const int gx   = gridDim.x;
    const int nwg  = gx * gridDim.y;
    const int orig = blockIdx.y * gx + blockIdx.x;
    const int qq = nwg >> 3, rr = nwg & 7;
    const int xcd = orig & 7, lid = orig >> 3;
    const int wg = (xcd < rr ? xcd * (qq + 1) : rr * (qq + 1) + (xcd - rr) * qq) + lid;
    const long m0 = (long)(wg / gx) * 128;
    const long n0 = (long)(wg % gx) * 128;

    const bool wact = ((int)n0 + (wc << 6)) < nvalid;

    f32x4 acc[4][4];
    #pragma unroll
    for (int i = 0; i < 4; i++)
        #pragma unroll
        for (int j = 0; j < 4; j++) acc[i][j] = (f32x4){0.f, 0.f, 0.f, 0.f};

    // staging: per K-tile(32) each matrix tile is 8KB = 2 x (256 thr x 16B)
    // thread -> row r0 = tid>>2 (and r0+64), 16B slot sl = tid&3,
    // inverse-swizzled source slot ssl = sl ^ ((r0>>1)&3)  (same for r0+64)
    const int r0  = tid >> 2;
    const int sl  = tid & 3;
    const int ssl = sl ^ ((r0 >> 1) & 3);
    const __hip_bfloat16* Agb = A  + (m0 + r0) * (long)K + (ssl << 3);
    const __hip_bfloat16* Bgb = Bt + (n0 + r0) * (long)K + (ssl << 3);
    char* dA = smraw + r0 * 64 + sl * 16;            // linear LDS dest
    char* dB = dA + 8192;

    const int frow = lane & 15;
    const int fks  = lane >> 4;                      // 0..3 (k-slot within K=32)
    const int colA = (fks ^ ((frow >> 1) & 3)) << 4; // swizzled 16B slot -> byte offset

    auto STAGE = [&](int b, int kt) {
        const long ko = (long)kt << 5;
        gload_lds16(Agb + ko,                dA + b * 16384);
        gload_lds16(Agb + 64 * (long)K + ko, dA + b * 16384 + 4096);
        gload_lds16(Bgb + ko,                dB + b * 16384);
        gload_lds16(Bgb + 64 * (long)K + ko, dB + b * 16384 + 4096);
    };

    const int nt = K >> 5;                           // >= 20 at all call sites
    STAGE(0, 0);
    for (int t = 0; t < nt; ++t) {
        asm volatile("s_waitcnt vmcnt(0)" ::: "memory");   // own tile-t loads (all in flight)
        __builtin_amdgcn_s_barrier();        // everyone's tile-t landed; compute(t-1) done
        __builtin_amdgcn_sched_barrier(0);
        if (t + 1 < nt) STAGE((t + 1) & 1, t + 1);   // overlaps compute(t)
        if (wact) {
            const char* pA = smraw + (t & 1) * 16384;
            const char* pB = pA + 8192;
            short8 af[4], bfr[4];
            #pragma unroll
            for (int mi = 0; mi < 4; ++mi)
                af[mi] = *(const short8*)(pA + ((wr << 6) + (mi << 4) + frow) * 64 + colA);
            #pragma unroll
            for (int nj = 0; nj < 4; ++nj)
                bfr[nj] = *(const short8*)(pB + ((wc << 6) + (nj << 4) + frow) * 64 + colA);
            __builtin_amdgcn_s_setprio(1);
            #pragma unroll
            for (int mi = 0; mi < 4; ++mi)
                #pragma unroll
                for (int nj = 0; nj < 4; ++nj)       // SWAPPED: D rows <- N, cols <- M
                    acc[mi][nj] = __builtin_amdgcn_mfma_f32_16x16x32_bf16(
                        bfr[nj], af[mi], acc[mi][nj], 0, 0, 0);
            __builtin_amdgcn_s_setprio(0);
        }
    }

    if (!wact) return;
    // epilogue: lane holds m = frow (fixed), n = base + fks*4 + r  (4 consecutive cols)
    const int nlim = (ncf > ncb) ? ncf : ncb;
    #pragma unroll
    for (int mi = 0; mi < 4; ++mi) {
        const long row = m0 + (wr << 6) + (mi << 4) + frow;
        #pragma unroll
        for (int nj = 0; nj < 4; ++nj) {
            const int n = (int)n0 + (wc << 6) + (nj << 4) + (fks << 2);
            if (n >= nlim) continue;
            f32x4 v = acc[mi][nj];
            if (bias) {
                const f32x4 bv = *(const f32x4*)&bias[n];
                v += bv;
            }
            if (act_gelu) {
                v[0] = gelu_f(v[0]); v[1] = gelu_f(v[1]); v[2] = gelu_f(v[2]); v[3] = gelu_f(v[3]);
            }
            if (mode == 1) {
                // NCHW scatter: out[(b*64 + n+r)*3136 + pos], row = b*3136 + pos
                const int b = (int)(row / 3136), pos = (int)(row % 3136);
                #pragma unroll
                for (int r = 0; r < 4; ++r)
                    Cf[(long)(b * 64 + n + r) * 3136 + pos] = v[r];
                continue;
            }
            if (resid && n < ncf) v += *(const f32x4*)&resid[row * (long)ldc + n];
            if (Cf && n < ncf) *(f32x4*)&Cf[row * (long)ldc + n] = v;
            if (Cb && n < ncb) {
                short4 p;
                p.x = (short)__bfloat16_as_short(__float2bfloat16(v[0]));
                p.y = (short)__bfloat16_as_short(__float2bfloat16(v[1]));
                p.z = (short)__bfloat16_as_short(__float2bfloat16(v[2]));
                p.w = (short)__bfloat16_as_short(__float2bfloat16(v[3]));
                *(short4*)&Cb[row * (long)ldb + col_off + n] = p;
            }
        }
    }
}

// ---------------- window attention (per window-head, fp32 in LDS) ----------------
__global__ __launch_bounds__(256)
void attn_kernel(const __hip_bfloat16* __restrict__ qkv, __hip_bfloat16* __restrict__ o,
                 int shift) {
    __shared__ __align__(16) float qT[80][52];
    __shared__ __align__(16) float kT[80][52];
    __shared__ __align__(16) float vs[50][80];
    __shared__ __align__(16) float ss[49][52];
    __shared__ int toks[49];
    __shared__ int rid[49];

    const int tid = threadIdx.x;
    const int win = blockIdx.x >> 3;
    const int hd  = blockIdx.x & 7;
    const int b   = win >> 6;
    const int wh  = (win >> 3) & 7;
    const int ww  = win & 7;

    if (tid < 49) {
        int i = tid / 7, j = tid % 7;
        int ph = wh * 7 + i, pw = ww * 7 + j;
        int sh = ph + shift; if (sh >= 56) sh -= 56;
        int sw = pw + shift; if (sw >= 56) sw -= 56;
        toks[tid] = (b * 56 + sh) * 56 + sw;
        int rh = (ph < 49) ? 0 : ((ph < 53) ? 1 : 2);
        int rw = (pw < 49) ? 0 : ((pw < 53) ? 1 : 2);
        rid[tid] = rh * 3 + rw;
    }
    for (int i = tid; i < 80 * 3; i += 256) {
        int d = i / 3, cc = 49 + (i % 3);
        qT[d][cc] = 0.f; kT[d][cc] = 0.f;
    }
    __syncthreads();
    for (int idx = tid; idx < 49 * 80; idx += 256) {
        int t = idx / 80, d = idx % 80;
        long base = (long)toks[t] * 1920 + hd * 80 + d;
        qT[d][t] = __bfloat162float(qkv[base]);
        kT[d][t] = __bfloat162float(qkv[base + 640]);
        vs[t][d] = __bfloat162float(qkv[base + 1280]);
    }
    __syncthreads();
    const float scale = 0.11180339887498948f;
    for (int p = tid; p < 49 * 13; p += 256) {
        int t = p / 13, j0 = (p % 13) * 4;
        float4 a = {0.f, 0.f, 0.f, 0.f};
        #pragma unroll
        for (int d = 0; d < 80; d++) {
            float qv = qT[d][t];
            float4 kv = *(const float4*)&kT[d][j0];
            a.x += qv * kv.x; a.y += qv * kv.y; a.z += qv * kv.z; a.w += qv * kv.w;
        }
        a.x *= scale; a.y *= scale; a.z *= scale; a.w *= scale;
        *(float4*)&ss[t][j0] = a;
    }
    __syncthreads();
    // parallel softmax: 4 lanes per row (196 threads), shfl_xor reduce within 4-lane group
    if (tid < 196) {
        const int r = tid >> 2, sub = tid & 3;
        const int j0 = sub * 13;
        const int j1 = (sub == 3) ? 10 : 13;
        const int myr = rid[r];
        float mx = -1e30f;
        for (int i = 0; i < j1; i++) {
            float v = ss[r][j0 + i];
            if (shift && rid[j0 + i] != myr) v = -1e9f;
            ss[r][j0 + i] = v;
            mx = fmaxf(mx, v);
        }
        mx = fmaxf(mx, __shfl_xor(mx, 1));
        mx = fmaxf(mx, __shfl_xor(mx, 2));
        float sum = 0.f;
        for (int i = 0; i < j1; i++) {
            float e = __expf(ss[r][j0 + i] - mx);
            ss[r][j0 + i] = e;
            sum += e;
        }
        sum += __shfl_xor(sum, 1);
        sum += __shfl_xor(sum, 2);
        const float inv = 1.f / sum;
        for (int i = 0; i < j1; i++) ss[r][j0 + i] *= inv;
    }
    __syncthreads();
    for (int p = tid; p < 49 * 20; p += 256) {
        int t = p / 20, dv = (p % 20) * 4;
        float4 a = {0.f, 0.f, 0.f, 0.f};
        for (int j = 0; j < 49; j++) {
            float w = ss[t][j];
            float4 vv = *(const float4*)&vs[j][dv];
            a.x += w * vv.x; a.y += w * vv.y; a.z += w * vv.z; a.w += w * vv.w;
        }
        long base = (long)toks[t] * DD + hd * 80 + dv;
        o[base + 0] = __float2bfloat16(a.x);
        o[base + 1] = __float2bfloat16(a.y);
        o[base + 2] = __float2bfloat16(a.z);
        o[base + 3] = __float2bfloat16(a.w);
    }
}

// ---------------- inverse NSCT: 4 channels per thread, float4 loads ----------------
__global__ __launch_bounds__(256)
void ict_kernel(const float* __restrict__ y, const float* __restrict__ filt,
                __hip_bfloat16* __restrict__ ayc) {
    __shared__ float sf[225];
    for (int i = threadIdx.x; i < 225; i += 256) sf[i] = filt[i];
    __syncthreads();
    int id = blockIdx.x * 256 + threadIdx.x;   // NTOK * 16
    int c4 = (id & 15) << 2;
    int pix = id >> 4;
    int w = pix % 56, h = (pix / 56) % 56, b = pix / 3136;
    float4 a = {0.f, 0.f, 0.f, 0.f};
    #pragma unroll
    for (int dy = 0; dy < 5; dy++) {
        int hy = h + dy - 2;
        if (hy < 0 || hy >= 56) continue;
        #pragma unroll
        for (int dx = 0; dx < 5; dx++) {
            int wx = w + dx - 2;
            if (wx < 0 || wx >= 56) continue;
            const float* yr = y + ((long)(b * 56 + hy) * 56 + wx) * DD + c4;
            #pragma unroll
            for (int band = 0; band < 9; band++) {
                const float f = sf[band*25 + dy*5 + dx];
                const float4 vv = *(const float4*)&yr[band * 64];
                a.x += vv.x * f; a.y += vv.y * f; a.z += vv.z * f; a.w += vv.w * f;
            }
        }
    }
    short4 p;
    p.x = (short)__bfloat16_as_short(__float2bfloat16(a.x));
    p.y = (short)__bfloat16_as_short(__float2bfloat16(a.y));
    p.z = (short)__bfloat16_as_short(__float2bfloat16(a.z));
    p.w = (short)__bfloat16_as_short(__float2bfloat16(a.w));
    *(short4*)&ayc[(long)pix * DD + c4] = p;
}

// ---------------- host ----------------
extern "C" void kernel_launch(void* const* d_in, const int* in_sizes, int n_in,
                              void* d_out, int out_size, void* d_ws, size_t ws_size,
                              hipStream_t stream) {
    (void)in_sizes; (void)n_in; (void)out_size; (void)ws_size;
    const float* x      = (const float*)d_in[0];
    const float* ln1_g  = (const float*)d_in[1];
    const float* ln1_b  = (const float*)d_in[2];
    const float* qkv_w  = (const float*)d_in[3];
    const float* qkv_b  = (const float*)d_in[4];
    const float* proj_w = (const float*)d_in[5];
    const float* proj_b = (const float*)d_in[6];
    const float* ln2_g  = (const float*)d_in[7];
    const float* ln2_b  = (const float*)d_in[8];
    const float* fc1_w  = (const float*)d_in[9];
    const float* fc1_b  = (const float*)d_in[10];
    const float* fc2_w  = (const float*)d_in[11];
    const float* fc2_b  = (const float*)d_in[12];
    const float* lin_w  = (const float*)d_in[13];
    const float* lin_b  = (const float*)d_in[14];
    const float* conv_w = (const float*)d_in[15];
    const float* conv_b = (const float*)d_in[16];

    char* ws = (char*)d_ws;
    size_t off = 0;
    auto alloc = [&](size_t bytes) -> void* {
        void* p = ws + off;
        off += (bytes + 255) & ~(size_t)255;
        return p;
    };
    float* filt   = (float*)alloc(225 * 4);
    float* linbp  = (float*)alloc(640 * 4);
    float* convbp = (float*)alloc(128 * 4);
    __hip_bfloat16* qkvWt[2], *projWt[2], *fc1Wt[2], *fc2Wt[2];
    for (int i = 0; i < 2; i++) qkvWt[i] = (__hip_bfloat16*)alloc(1920L * 640 * 2);
    for (int i = 0; i < 2; i++) projWt[i] = (__hip_bfloat16*)alloc(640L * 640 * 2);
    for (int i = 0; i < 2; i++) fc1Wt[i] = (__hip_bfloat16*)alloc(2560L * 640 * 2);
    for (int i = 0; i < 2; i++) fc2Wt[i] = (__hip_bfloat16*)alloc(640L * 2560 * 2);
    __hip_bfloat16* linWt  = (__hip_bfloat16*)alloc(640L * 640 * 2);   // N padded 576->640
    __hip_bfloat16* convWt = (__hip_bfloat16*)alloc(128L * 640 * 2);   // N padded 64->128
    float* x3 = (float*)alloc((long)NTOK * DD * 4);
    __hip_bfloat16* bufA = (__hip_bfloat16*)alloc((long)NTOK * DD * 2);
    char* bufB = (char*)alloc((long)NTOK * 2560 * 2);
    __hip_bfloat16* qkv = (__hip_bfloat16*)bufB;
    __hip_bfloat16* h2  = (__hip_bfloat16*)bufB;
    float* ybuf = (float*)bufB;
    __hip_bfloat16* ayc = (__hip_bfloat16*)(bufB + (long)NTOK * DD * 4);

    hipFuncSetAttribute((const void*)gemm128_kernel,
                        hipFuncAttributeMaxDynamicSharedMemorySize, 32768);

    dim3 tb(32, 8);
    init_consts<<<1, 256, 0, stream>>>(filt, linbp, lin_b, convbp, conv_b);
    for (int i = 0; i < 2; i++) {
        wtrans_kernel<<<dim3(60, 20), tb, 0, stream>>>(qkv_w + (long)i*640*1920, qkvWt[i], 640, 1920);
        wtrans_kernel<<<dim3(20, 20), tb, 0, stream>>>(proj_w + (long)i*640*640,  projWt[i], 640, 640);
        wtrans_kernel<<<dim3(80, 20), tb, 0, stream>>>(fc1_w + (long)i*640*2560, fc1Wt[i], 640, 2560);
        wtrans_kernel<<<dim3(20, 80), tb, 0, stream>>>(fc2_w + (long)i*2560*640, fc2Wt[i], 2560, 640);
    }
    wtrans_kernel<<<dim3(20, 20), tb, 0, stream>>>(lin_w, linWt, 640, 576);
    wcast_kernel<<<320, 256, 0, stream>>>(conv_w, convWt, 64 * 640, 128 * 640);

    prep_kernel<<<6272, 256, 0, stream>>>(x, filt, x3);

    for (int i = 0; i < 2; i++) {
        int shift = i ? 3 : 0;
        ln_kernel<<<6272, 256, 0, stream>>>(x3, ln1_g + i*640, ln1_b + i*640, bufA);
        // qkv: N=1920 exact (15 col-tiles), bf16 out
        gemm128_kernel<<<dim3(15, 196), 256, 32768, stream>>>(bufA, qkvWt[i], qkv_b + i*1920,
            nullptr, nullptr, qkv, 640, 0, 0, 1920, 0, 1920, 0, 1920, 0);
        attn_kernel<<<4096, 256, 0, stream>>>(qkv, bufA, shift);
        // proj: N=640 exact, fp32 out + resid into x3
        gemm128_kernel<<<dim3(5, 196), 256, 32768, stream>>>(bufA, projWt[i], proj_b + i*640,
            x3, x3, nullptr, 640, 640, 640, 0, 0, 0, 0, 640, 0);
        ln_kernel<<<6272, 256, 0, stream>>>(x3, ln2_g + i*640, ln2_b + i*640, bufA);
        // fc1: N=2560 exact, gelu, bf16 out
        gemm128_kernel<<<dim3(20, 196), 256, 32768, stream>>>(bufA, fc1Wt[i], fc1_b + i*2560,
            nullptr, nullptr, h2, 640, 0, 0, 2560, 0, 2560, 1, 2560, 0);
        // fc2: N=640 exact, K=2560, resid into x3; last iter also mirrors bf16 into bufA
        gemm128_kernel<<<dim3(5, 196), 256, 32768, stream>>>(h2, fc2Wt[i], fc2_b + i*640,
            x3, x3, (i == 1) ? bufA : nullptr, 2560, 640, 640, 640, 0, (i == 1) ? 640 : 0, 0, 640, 0);
    }
    // lin: fp32 out (640 cols, 576 valid) + bf16 mirror into ayc cols [64,640)
    gemm128_kernel<<<dim3(5, 196), 256, 32768, stream>>>(bufA, linWt, linbp,
        nullptr, ybuf, ayc, 640, 640, 640, 640, 64, 576, 0, 576, 0);
    ict_kernel<<<1568, 256, 0, stream>>>(ybuf, filt, ayc);
    // conv: N=128 (64 valid), direct NCHW store into d_out (fuses unpack)
    gemm128_kernel<<<dim3(1, 196), 256, 32768, stream>>>(ayc, convWt, convbp,
        nullptr, (float*)d_out, nullptr, 640, 0, 64, 0, 0, 0, 0, 64, 1);
}

// Round 13
// 1336.908 us; speedup vs baseline: 2.4838x; 1.0263x over previous
//
#include <hip/hip_runtime.h>
#include <hip/hip_bf16.h>
#include <math.h>

// ---------------- types ----------------
typedef __attribute__((ext_vector_type(4))) float f32x4;
typedef __attribute__((ext_vector_type(8))) short short8;

#define NTOK 25088   // B*H*W = 8*56*56
#define DD   640

__device__ __forceinline__ void gload_lds16(const void* g, void* l) {
    __builtin_amdgcn_global_load_lds((const __attribute__((address_space(1))) void*)g,
                                     (__attribute__((address_space(3))) void*)l,
                                     16, 0, 0);
}

// exact rewrite of tanh-gelu: 0.5t(1+tanh(v)) = t * sigmoid(2v)
__device__ __forceinline__ float gelu_f(float t) {
    float u = 1.5957691216057308f * (t + 0.044715f * t * t * t);
    float e = __builtin_amdgcn_exp2f(u * -1.4426950408889634f);   // exp(-u)
    return t / (1.f + e);
}

__device__ __forceinline__ float bf2f(short u) {
    union { unsigned int i; float f; } cv;
    cv.i = ((unsigned int)(unsigned short)u) << 16;
    return cv.f;
}

// ---------------- constants init: NSCT filters + padded biases ----------------
__global__ void init_consts(float* __restrict__ filt, float* __restrict__ linbp,
                            const float* __restrict__ lin_b, float* __restrict__ convbp,
                            const float* __restrict__ conv_b) {
    int t = threadIdx.x;
    if (t == 0) {
        float g[25]; float s = 0.f;
        for (int i = 0; i < 5; i++) for (int j = 0; j < 5; j++) {
            float yy = (float)(i - 2), xx = (float)(j - 2);
            float v = expf(-(xx*xx + yy*yy) * 0.25f);
            g[i*5+j] = v; s += v;
        }
        for (int i = 0; i < 25; i++) { g[i] /= s; filt[i] = g[i]; }
        for (int k = 0; k < 8; k++) {
            float th = (float)k * 3.14159265358979323846f / 8.f;
            float ct = cosf(th), st = sinf(th);
            float d[25]; float mean = 0.f;
            for (int i = 0; i < 5; i++) for (int j = 0; j < 5; j++) {
                float yy = (float)(i - 2), xx = (float)(j - 2);
                d[i*5+j] = (ct*xx + st*yy) * g[i*5+j];
                mean += d[i*5+j];
            }
            mean *= (1.f/25.f);
            float ss = 0.f;
            for (int i = 0; i < 25; i++) { d[i] -= mean; ss += d[i]*d[i]; }
            ss = sqrtf(ss);
            for (int i = 0; i < 25; i++) filt[(k+1)*25 + i] = d[i] / ss;
        }
    }
    for (int i = t; i < 640; i += 256) linbp[i]  = (i < 576) ? lin_b[i]  : 0.f;
    for (int i = t; i < 128; i += 256) convbp[i] = (i < 64)  ? conv_b[i] : 0.f;
}

// ---------------- weight transpose+cast: dst[n][k] = bf16(src[k][n]), zero-pad n>=Nsrc ----------------
__global__ __launch_bounds__(256)
void wtrans_kernel(const float* __restrict__ src, __hip_bfloat16* __restrict__ dst,
                   int K, int Nsrc) {
    __shared__ float tile[32][33];
    const int n0 = blockIdx.x * 32;
    const int k0 = blockIdx.y * 32;
    const int tx = threadIdx.x, ty = threadIdx.y;
    #pragma unroll
    for (int r = ty; r < 32; r += 8) {
        int k = k0 + r, n = n0 + tx;
        tile[r][tx] = (n < Nsrc) ? src[(long)k * Nsrc + n] : 0.f;
    }
    __syncthreads();
    #pragma unroll
    for (int r = ty; r < 32; r += 8) {
        int n = n0 + r, k = k0 + tx;
        dst[(long)n * K + k] = __float2bfloat16(tile[tx][r]);
    }
}

__global__ void wcast_kernel(const float* __restrict__ src, __hip_bfloat16* __restrict__ dst,
                             int count, int total) {
    int i = blockIdx.x * 256 + threadIdx.x;
    if (i < total) dst[i] = __float2bfloat16(i < count ? src[i] : 0.f);
}

// ---- prep: relu + 9-band NSCT conv + concat -> x3 fp32 AND fused LN1(layer0) -> bufA bf16 ----
// Each wave (64 lanes) holds exactly one pixel's full 640-ch row (lane = channel c; lane
// holds bands 0..8 at c + center copy). LN reduce = wave-wide shfl_xor. Saves one ln pass.
__global__ __launch_bounds__(256)
void prep_kernel(const float* __restrict__ x, const float* __restrict__ filt,
                 float* __restrict__ x3, const float* __restrict__ g1,
                 const float* __restrict__ b1, __hip_bfloat16* __restrict__ lnout) {
    __shared__ float sf[225];
    for (int i = threadIdx.x; i < 225; i += 256) sf[i] = filt[i];
    __syncthreads();
    int id = blockIdx.x * 256 + threadIdx.x;   // B*H*W*C
    int c = id & 63;
    int pix = id >> 6;
    int w = pix % 56, h = (pix / 56) % 56, b = pix / 3136;
    const float* xp = x + (long)(b * 64 + c) * 3136;
    float nb[25];
    #pragma unroll
    for (int dy = 0; dy < 5; dy++) {
        int hy = h + dy - 2;
        #pragma unroll
        for (int dx = 0; dx < 5; dx++) {
            int wx = w + dx - 2;
            float v = 0.f;
            if (hy >= 0 && hy < 56 && wx >= 0 && wx < 56) v = fmaxf(xp[hy*56 + wx], 0.f);
            nb[dy*5 + dx] = v;
        }
    }
    float bo[9];
    float* orow = x3 + (long)pix * DD;
    float s = 0.f, s2 = 0.f;
    #pragma unroll
    for (int band = 0; band < 9; band++) {
        float a = 0.f;
        #pragma unroll
        for (int t = 0; t < 25; t++) a += nb[t] * sf[band*25 + t];
        bo[band] = a;
        orow[band*64 + c] = a;
        s += a; s2 += a * a;
    }
    const float ctr = nb[12];
    orow[576 + c] = ctr;                      // relu(x) center copy
    s += ctr; s2 += ctr * ctr;
    // wave-wide LN (this wave == this pixel's 64 channels x 10 vals)
    #pragma unroll
    for (int o = 32; o > 0; o >>= 1) { s += __shfl_xor(s, o); s2 += __shfl_xor(s2, o); }
    const float mean = s * (1.f/640.f);
    const float var  = s2 * (1.f/640.f) - mean * mean;
    const float inv  = 1.f / sqrtf(var + 1e-5f);
    __hip_bfloat16* ob = lnout + (long)pix * DD;
    #pragma unroll
    for (int band = 0; band < 9; band++) {
        int ci = band*64 + c;
        ob[ci] = __float2bfloat16((bo[band] - mean) * inv * g1[ci] + b1[ci]);
    }
    ob[576 + c] = __float2bfloat16((ctr - mean) * inv * g1[576 + c] + b1[576 + c]);
}

// ---------------- LayerNorm (per-token over 640) -> bf16 ----------------
__global__ __launch_bounds__(256)
void ln_kernel(const float* __restrict__ xin, const float* __restrict__ g,
               const float* __restrict__ bt, __hip_bfloat16* __restrict__ out) {
    const int lane = threadIdx.x & 63;
    const long tok = (long)blockIdx.x * 4 + (threadIdx.x >> 6);
    const float* xr = xin + tok * DD;
    float v[10]; float s = 0.f, s2 = 0.f;
    #pragma unroll
    for (int i = 0; i < 10; i++) { float t = xr[lane + (i << 6)]; v[i] = t; s += t; s2 += t*t; }
    #pragma unroll
    for (int o = 32; o > 0; o >>= 1) { s += __shfl_down(s, o); s2 += __shfl_down(s2, o); }
    s = __shfl(s, 0); s2 = __shfl(s2, 0);
    const float mean = s * (1.f/640.f);
    const float var  = s2 * (1.f/640.f) - mean * mean;
    const float inv  = 1.f / sqrtf(var + 1e-5f);
    __hip_bfloat16* orow = out + tok * DD;
    #pragma unroll
    for (int i = 0; i < 10; i++) {
        int c = lane + (i << 6);
        orow[c] = __float2bfloat16((v[i] - mean) * inv * g[c] + bt[c]);
    }
}

// ===== 128x128 GEMM, BK=32, double-buffer 32KB, 4 blocks/CU, K-loop unrolled x2 =====
// C[M,N] = A[M,K](bf16) @ Bt[N,K]^T(bf16); 256 thr = 4 waves (2M x 2N), per-wave 64x64.
// R12 counters: VALUBusy 45% (top pipe) — runtime (t&1) buffer toggle forced per-iter
// address recompute. Unroll x2 makes buffer offsets compile-time so all 8 LDS read
// addresses + staging addresses are loop-invariant (issue-bound regime at 16 waves/CU).
// __launch_bounds__(256,3): reg budget 170, no spill (R11 lesson); runtime occupancy 4 blk/CU.
// Swizzle: 16B slot ^= (row>>1)&3 on global source + LDS read (rule #21, 0 conflicts).
// mode: 0 = normal stores; 1 = NCHW scatter store (final conv, fuses unpack).
__global__ __launch_bounds__(256, 3)
void gemm128_kernel(const __hip_bfloat16* __restrict__ A,
                    const __hip_bfloat16* __restrict__ Bt,
                    const float* __restrict__ bias,
                    const float* __restrict__ resid,
                    float* __restrict__ Cf,
                    __hip_bfloat16* __restrict__ Cb,
                    int K, int ldc, int ncf, int ldb, int col_off, int ncb,
                    int act_gelu, int nvalid, int mode) {
    extern __shared__ __align__(16) char smraw[];   // 2 x 16384B: [A 8192 | B 8192]

    const int tid  = threadIdx.x;
    const int lane = tid & 63;
    const int wv   = tid >> 6;
    const int wr   = wv >> 1;          // 0..1  (M half: 64 rows)
    const int wc   = wv & 1;           // 0..1  (N half: 64 cols)

    // ---- bijective XCD-aware block remap (m204) ----
    const int gx   = gridDim.x;
    const int nwg  = gx * gridDim.y;
    const int orig = blockIdx.y * gx + blockIdx.x;
    const int qq = nwg >> 3, rr = nwg & 7;
    const int xcd = orig & 7, lid = orig >> 3;
    const int wg = (xcd < rr ? xcd * (qq + 1) : rr * (qq + 1) + (xcd - rr) * qq) + lid;
    const long m0 = (long)(wg / gx) * 128;
    const long n0 = (long)(wg % gx) * 128;

    const bool wact = ((int)n0 + (wc << 6)) < nvalid;

    f32x4 acc[4][4];
    #pragma unroll
    for (int i = 0; i < 4; i++)
        #pragma unroll
        for (int j = 0; j < 4; j++) acc[i][j] = (f32x4){0.f, 0.f, 0.f, 0.f};

    // staging: per K-tile(32) each matrix tile is 8KB = 2 x (256 thr x 16B)
    const int r0  = tid >> 2;
    const int sl  = tid & 3;
    const int ssl = sl ^ ((r0 >> 1) & 3);
    const __hip_bfloat16* Agb = A  + (m0 + r0) * (long)K + (ssl << 3);
    const __hip_bfloat16* Bgb = Bt + (n0 + r0) * (long)K + (ssl << 3);
    char* dA = smraw + r0 * 64 + sl * 16;            // linear LDS dest
    char* dB = dA + 8192;

    const int frow = lane & 15;
    const int fks  = lane >> 4;                      // 0..3 (k-slot within K=32)
    const int colA = (fks ^ ((frow >> 1) & 3)) << 4; // swizzled 16B slot -> byte offset

    auto STAGE = [&](int boff, int kt) {
        const long ko = (long)kt << 5;
        gload_lds16(Agb + ko,                dA + boff);
        gload_lds16(Agb + 64 * (long)K + ko, dA + boff + 4096);
        gload_lds16(Bgb + ko,                dB + boff);
        gload_lds16(Bgb + 64 * (long)K + ko, dB + boff + 4096);
    };

#define COMPUTE(BUFOFF)                                                                     \
    do {                                                                                    \
        if (wact) {                                                                         \
            const char* pA = smraw + (BUFOFF);                                              \
            const char* pB = pA + 8192;                                                     \
            short8 af[4], bfr[4];                                                           \
            _Pragma("unroll")                                                               \
            for (int mi = 0; mi < 4; ++mi)                                                  \
                af[mi] = *(const short8*)(pA + ((wr << 6) + (mi << 4) + frow) * 64 + colA); \
            _Pragma("unroll")                                                               \
            for (int nj = 0; nj < 4; ++nj)                                                  \
                bfr[nj] = *(const short8*)(pB + ((wc << 6) + (nj << 4) + frow) * 64 + colA);\
            __builtin_amdgcn_s_setprio(1);                                                  \
            _Pragma("unroll")                                                               \
            for (int mi = 0; mi < 4; ++mi)                                                  \
                _Pragma("unroll")                                                           \
                for (int nj = 0; nj < 4; ++nj)  /* SWAPPED: D rows <- N, cols <- M */       \
                    acc[mi][nj] = __builtin_amdgcn_mfma_f32_16x16x32_bf16(                  \
                        bfr[nj], af[mi], acc[mi][nj], 0, 0, 0);                             \
            __builtin_amdgcn_s_setprio(0);                                                  \
        }                                                                                   \
    } while (0)

    const int nt = K >> 5;                           // EVEN at all call sites (20, 80)
    STAGE(0, 0);
    for (int t = 0; t < nt; t += 2) {
        asm volatile("s_waitcnt vmcnt(0)" ::: "memory");   // tile t landed (own loads)
        __builtin_amdgcn_s_barrier();
        __builtin_amdgcn_sched_barrier(0);
        if (t + 1 < nt) STAGE(16384, t + 1);
        COMPUTE(0);
        asm volatile("s_waitcnt vmcnt(0)" ::: "memory");   // tile t+1 landed
        __builtin_amdgcn_s_barrier();
        __builtin_amdgcn_sched_barrier(0);
        if (t + 2 < nt) STAGE(0, t + 2);
        COMPUTE(16384);
    }
#undef COMPUTE

    if (!wact) return;
    // epilogue: lane holds m = frow (fixed), n = base + fks*4 + r  (4 consecutive cols)
    const int nlim = (ncf > ncb) ? ncf : ncb;
    #pragma unroll
    for (int mi = 0; mi < 4; ++mi) {
        const long row = m0 + (wr << 6) + (mi << 4) + frow;
        #pragma unroll
        for (int nj = 0; nj < 4; ++nj) {
            const int n = (int)n0 + (wc << 6) + (nj << 4) + (fks << 2);
            if (n >= nlim) continue;
            f32x4 v = acc[mi][nj];
            if (bias) {
                const f32x4 bv = *(const f32x4*)&bias[n];
                v += bv;
            }
            if (act_gelu) {
                v[0] = gelu_f(v[0]); v[1] = gelu_f(v[1]); v[2] = gelu_f(v[2]); v[3] = gelu_f(v[3]);
            }
            if (mode == 1) {
                // NCHW scatter: out[(b*64 + n+r)*3136 + pos], row = b*3136 + pos
                const int b = (int)(row / 3136), pos = (int)(row % 3136);
                #pragma unroll
                for (int r = 0; r < 4; ++r)
                    Cf[(long)(b * 64 + n + r) * 3136 + pos] = v[r];
                continue;
            }
            if (resid && n < ncf) v += *(const f32x4*)&resid[row * (long)ldc + n];
            if (Cf && n < ncf) *(f32x4*)&Cf[row * (long)ldc + n] = v;
            if (Cb && n < ncb) {
                short4 p;
                p.x = (short)__bfloat16_as_short(__float2bfloat16(v[0]));
                p.y = (short)__bfloat16_as_short(__float2bfloat16(v[1]));
                p.z = (short)__bfloat16_as_short(__float2bfloat16(v[2]));
                p.w = (short)__bfloat16_as_short(__float2bfloat16(v[3]));
                *(short4*)&Cb[row * (long)ldb + col_off + n] = p;
            }
        }
    }
}

// ---------------- window attention (per window-head, fp32 in LDS) ----------------
__global__ __launch_bounds__(256)
void attn_kernel(const __hip_bfloat16* __restrict__ qkv, __hip_bfloat16* __restrict__ o,
                 int shift) {
    __shared__ __align__(16) float qT[80][52];
    __shared__ __align__(16) float kT[80][52];
    __shared__ __align__(16) float vs[50][80];
    __shared__ __align__(16) float ss[49][52];
    __shared__ int toks[49];
    __shared__ int rid[49];

    const int tid = threadIdx.x;
    const int win = blockIdx.x >> 3;
    const int hd  = blockIdx.x & 7;
    const int b   = win >> 6;
    const int wh  = (win >> 3) & 7;
    const int ww  = win & 7;

    if (tid < 49) {
        int i = tid / 7, j = tid % 7;
        int ph = wh * 7 + i, pw = ww * 7 + j;
        int sh = ph + shift; if (sh >= 56) sh -= 56;
        int sw = pw + shift; if (sw >= 56) sw -= 56;
        toks[tid] = (b * 56 + sh) * 56 + sw;
        int rh = (ph < 49) ? 0 : ((ph < 53) ? 1 : 2);
        int rw = (pw < 49) ? 0 : ((pw < 53) ? 1 : 2);
        rid[tid] = rh * 3 + rw;
    }
    for (int i = tid; i < 80 * 3; i += 256) {
        int d = i / 3, cc = 49 + (i % 3);
        qT[d][cc] = 0.f; kT[d][cc] = 0.f;
    }
    __syncthreads();
    for (int idx = tid; idx < 49 * 80; idx += 256) {
        int t = idx / 80, d = idx % 80;
        long base = (long)toks[t] * 1920 + hd * 80 + d;
        qT[d][t] = __bfloat162float(qkv[base]);
        kT[d][t] = __bfloat162float(qkv[base + 640]);
        vs[t][d] = __bfloat162float(qkv[base + 1280]);
    }
    __syncthreads();
    const float scale = 0.11180339887498948f;
    for (int p = tid; p < 49 * 13; p += 256) {
        int t = p / 13, j0 = (p % 13) * 4;
        float4 a = {0.f, 0.f, 0.f, 0.f};
        #pragma unroll
        for (int d = 0; d < 80; d++) {
            float qv = qT[d][t];
            float4 kv = *(const float4*)&kT[d][j0];
            a.x += qv * kv.x; a.y += qv * kv.y; a.z += qv * kv.z; a.w += qv * kv.w;
        }
        a.x *= scale; a.y *= scale; a.z *= scale; a.w *= scale;
        *(float4*)&ss[t][j0] = a;
    }
    __syncthreads();
    // parallel softmax: 4 lanes per row (196 threads), shfl_xor reduce within 4-lane group
    if (tid < 196) {
        const int r = tid >> 2, sub = tid & 3;
        const int j0 = sub * 13;
        const int j1 = (sub == 3) ? 10 : 13;
        const int myr = rid[r];
        float mx = -1e30f;
        for (int i = 0; i < j1; i++) {
            float v = ss[r][j0 + i];
            if (shift && rid[j0 + i] != myr) v = -1e9f;
            ss[r][j0 + i] = v;
            mx = fmaxf(mx, v);
        }
        mx = fmaxf(mx, __shfl_xor(mx, 1));
        mx = fmaxf(mx, __shfl_xor(mx, 2));
        float sum = 0.f;
        for (int i = 0; i < j1; i++) {
            float e = __expf(ss[r][j0 + i] - mx);
            ss[r][j0 + i] = e;
            sum += e;
        }
        sum += __shfl_xor(sum, 1);
        sum += __shfl_xor(sum, 2);
        const float inv = 1.f / sum;
        for (int i = 0; i < j1; i++) ss[r][j0 + i] *= inv;
    }
    __syncthreads();
    for (int p = tid; p < 49 * 20; p += 256) {
        int t = p / 20, dv = (p % 20) * 4;
        float4 a = {0.f, 0.f, 0.f, 0.f};
        for (int j = 0; j < 49; j++) {
            float w = ss[t][j];
            float4 vv = *(const float4*)&vs[j][dv];
            a.x += w * vv.x; a.y += w * vv.y; a.z += w * vv.z; a.w += w * vv.w;
        }
        long base = (long)toks[t] * DD + hd * 80 + dv;
        o[base + 0] = __float2bfloat16(a.x);
        o[base + 1] = __float2bfloat16(a.y);
        o[base + 2] = __float2bfloat16(a.z);
        o[base + 3] = __float2bfloat16(a.w);
    }
}

// ---- inverse NSCT: reads bf16 y-mirror (ayc cols [64,640)), writes ayc cols [0,64) ----
__global__ __launch_bounds__(256)
void ict_kernel(__hip_bfloat16* ayc, const float* __restrict__ filt) {
    __shared__ float sf[225];
    for (int i = threadIdx.x; i < 225; i += 256) sf[i] = filt[i];
    __syncthreads();
    int id = blockIdx.x * 256 + threadIdx.x;   // NTOK * 16
    int c4 = (id & 15) << 2;
    int pix = id >> 4;
    int w = pix % 56, h = (pix / 56) % 56, b = pix / 3136;
    float4 a = {0.f, 0.f, 0.f, 0.f};
    #pragma unroll
    for (int dy = 0; dy < 5; dy++) {
        int hy = h + dy - 2;
        if (hy < 0 || hy >= 56) continue;
        #pragma unroll
        for (int dx = 0; dx < 5; dx++) {
            int wx = w + dx - 2;
            if (wx < 0 || wx >= 56) continue;
            const __hip_bfloat16* yr = ayc + ((long)(b * 56 + hy) * 56 + wx) * DD + 64 + c4;
            #pragma unroll
            for (int band = 0; band < 9; band++) {
                const float f = sf[band*25 + dy*5 + dx];
                const short4 sv = *(const short4*)&yr[band * 64];
                a.x += bf2f(sv.x) * f; a.y += bf2f(sv.y) * f;
                a.z += bf2f(sv.z) * f; a.w += bf2f(sv.w) * f;
            }
        }
    }
    short4 p;
    p.x = (short)__bfloat16_as_short(__float2bfloat16(a.x));
    p.y = (short)__bfloat16_as_short(__float2bfloat16(a.y));
    p.z = (short)__bfloat16_as_short(__float2bfloat16(a.z));
    p.w = (short)__bfloat16_as_short(__float2bfloat16(a.w));
    *(short4*)&ayc[(long)pix * DD + c4] = p;
}

// ---------------- host ----------------
extern "C" void kernel_launch(void* const* d_in, const int* in_sizes, int n_in,
                              void* d_out, int out_size, void* d_ws, size_t ws_size,
                              hipStream_t stream) {
    (void)in_sizes; (void)n_in; (void)out_size; (void)ws_size;
    const float* x      = (const float*)d_in[0];
    const float* ln1_g  = (const float*)d_in[1];
    const float* ln1_b  = (const float*)d_in[2];
    const float* qkv_w  = (const float*)d_in[3];
    const float* qkv_b  = (const float*)d_in[4];
    const float* proj_w = (const float*)d_in[5];
    const float* proj_b = (const float*)d_in[6];
    const float* ln2_g  = (const float*)d_in[7];
    const float* ln2_b  = (const float*)d_in[8];
    const float* fc1_w  = (const float*)d_in[9];
    const float* fc1_b  = (const float*)d_in[10];
    const float* fc2_w  = (const float*)d_in[11];
    const float* fc2_b  = (const float*)d_in[12];
    const float* lin_w  = (const float*)d_in[13];
    const float* lin_b  = (const float*)d_in[14];
    const float* conv_w = (const float*)d_in[15];
    const float* conv_b = (const float*)d_in[16];

    char* ws = (char*)d_ws;
    size_t off = 0;
    auto alloc = [&](size_t bytes) -> void* {
        void* p = ws + off;
        off += (bytes + 255) & ~(size_t)255;
        return p;
    };
    float* filt   = (float*)alloc(225 * 4);
    float* linbp  = (float*)alloc(640 * 4);
    float* convbp = (float*)alloc(128 * 4);
    __hip_bfloat16* qkvWt[2], *projWt[2], *fc1Wt[2], *fc2Wt[2];
    for (int i = 0; i < 2; i++) qkvWt[i] = (__hip_bfloat16*)alloc(1920L * 640 * 2);
    for (int i = 0; i < 2; i++) projWt[i] = (__hip_bfloat16*)alloc(640L * 640 * 2);
    for (int i = 0; i < 2; i++) fc1Wt[i] = (__hip_bfloat16*)alloc(2560L * 640 * 2);
    for (int i = 0; i < 2; i++) fc2Wt[i] = (__hip_bfloat16*)alloc(640L * 2560 * 2);
    __hip_bfloat16* linWt  = (__hip_bfloat16*)alloc(640L * 640 * 2);   // N padded 576->640
    __hip_bfloat16* convWt = (__hip_bfloat16*)alloc(128L * 640 * 2);   // N padded 64->128
    float* x3 = (float*)alloc((long)NTOK * DD * 4);
    __hip_bfloat16* bufA = (__hip_bfloat16*)alloc((long)NTOK * DD * 2);
    char* bufB = (char*)alloc((long)NTOK * 2560 * 2);
    __hip_bfloat16* qkv = (__hip_bfloat16*)bufB;
    __hip_bfloat16* h2  = (__hip_bfloat16*)bufB;
    __hip_bfloat16* ayc = (__hip_bfloat16*)(bufB + (long)NTOK * DD * 4);

    hipFuncSetAttribute((const void*)gemm128_kernel,
                        hipFuncAttributeMaxDynamicSharedMemorySize, 32768);

    dim3 tb(32, 8);
    init_consts<<<1, 256, 0, stream>>>(filt, linbp, lin_b, convbp, conv_b);
    for (int i = 0; i < 2; i++) {
        wtrans_kernel<<<dim3(60, 20), tb, 0, stream>>>(qkv_w + (long)i*640*1920, qkvWt[i], 640, 1920);
        wtrans_kernel<<<dim3(20, 20), tb, 0, stream>>>(proj_w + (long)i*640*640,  projWt[i], 640, 640);
        wtrans_kernel<<<dim3(80, 20), tb, 0, stream>>>(fc1_w + (long)i*640*2560, fc1Wt[i], 640, 2560);
        wtrans_kernel<<<dim3(20, 80), tb, 0, stream>>>(fc2_w + (long)i*2560*640, fc2Wt[i], 2560, 640);
    }
    wtrans_kernel<<<dim3(20, 20), tb, 0, stream>>>(lin_w, linWt, 640, 576);
    wcast_kernel<<<320, 256, 0, stream>>>(conv_w, convWt, 64 * 640, 128 * 640);

    // prep: writes x3 fp32 + fused LN1(layer0) bf16 into bufA
    prep_kernel<<<6272, 256, 0, stream>>>(x, filt, x3, ln1_g, ln1_b, bufA);

    for (int i = 0; i < 2; i++) {
        int shift = i ? 3 : 0;
        if (i == 1)   // layer 0's LN1 is fused into prep
            ln_kernel<<<6272, 256, 0, stream>>>(x3, ln1_g + i*640, ln1_b + i*640, bufA);
        // qkv: N=1920 exact (15 col-tiles), bf16 out
        gemm128_kernel<<<dim3(15, 196), 256, 32768, stream>>>(bufA, qkvWt[i], qkv_b + i*1920,
            nullptr, nullptr, qkv, 640, 0, 0, 1920, 0, 1920, 0, 1920, 0);
        attn_kernel<<<4096, 256, 0, stream>>>(qkv, bufA, shift);
        // proj: N=640 exact, fp32 out + resid into x3
        gemm128_kernel<<<dim3(5, 196), 256, 32768, stream>>>(bufA, projWt[i], proj_b + i*640,
            x3, x3, nullptr, 640, 640, 640, 0, 0, 0, 0, 640, 0);
        ln_kernel<<<6272, 256, 0, stream>>>(x3, ln2_g + i*640, ln2_b + i*640, bufA);
        // fc1: N=2560 exact, gelu, bf16 out
        gemm128_kernel<<<dim3(20, 196), 256, 32768, stream>>>(bufA, fc1Wt[i], fc1_b + i*2560,
            nullptr, nullptr, h2, 640, 0, 0, 2560, 0, 2560, 1, 2560, 0);
        // fc2: N=640 exact, K=2560, resid into x3; last iter also mirrors bf16 into bufA
        gemm128_kernel<<<dim3(5, 196), 256, 32768, stream>>>(h2, fc2Wt[i], fc2_b + i*640,
            x3, x3, (i == 1) ? bufA : nullptr, 2560, 640, 640, 640, 0, (i == 1) ? 640 : 0, 0, 640, 0);
    }
    // lin: bf16-only out into ayc cols [64,640)  (y mirror; no fp32 copy needed)
    gemm128_kernel<<<dim3(5, 196), 256, 32768, stream>>>(bufA, linWt, linbp,
        nullptr, nullptr, ayc, 640, 0, 0, 640, 64, 576, 0, 576, 0);
    ict_kernel<<<1568, 256, 0, stream>>>(ayc, filt);   // fills ayc cols [0,64)
    // conv: N=128 (64 valid), direct NCHW store into d_out (fuses unpack)
    gemm128_kernel<<<dim3(1, 196), 256, 32768, stream>>>(ayc, convWt, convbp,
        nullptr, (float*)d_out, nullptr, 640, 0, 64, 0, 0, 0, 0, 64, 1);
}

// Round 14
// 1294.024 us; speedup vs baseline: 2.5661x; 1.0331x over previous
//
#include <hip/hip_runtime.h>
#include <hip/hip_bf16.h>
#include <math.h>

// ---------------- types ----------------
typedef __attribute__((ext_vector_type(4))) float f32x4;
typedef __attribute__((ext_vector_type(8))) short short8;

#define NTOK 25088   // B*H*W = 8*56*56
#define DD   640

__device__ __forceinline__ void gload_lds16(const void* g, void* l) {
    __builtin_amdgcn_global_load_lds((const __attribute__((address_space(1))) void*)g,
                                     (__attribute__((address_space(3))) void*)l,
                                     16, 0, 0);
}

// exact rewrite of tanh-gelu: 0.5t(1+tanh(v)) = t * sigmoid(2v)
__device__ __forceinline__ float gelu_f(float t) {
    float u = 1.5957691216057308f * (t + 0.044715f * t * t * t);
    float e = __builtin_amdgcn_exp2f(u * -1.4426950408889634f);   // exp(-u)
    return t / (1.f + e);
}

__device__ __forceinline__ float bf2f(short u) {
    union { unsigned int i; float f; } cv;
    cv.i = ((unsigned int)(unsigned short)u) << 16;
    return cv.f;
}
__device__ __forceinline__ short f2bf(float f) {
    return (short)__bfloat16_as_short(__float2bfloat16(f));
}

// ---------------- constants init: NSCT filters + padded biases ----------------
__global__ void init_consts(float* __restrict__ filt, float* __restrict__ linbp,
                            const float* __restrict__ lin_b, float* __restrict__ convbp,
                            const float* __restrict__ conv_b) {
    int t = threadIdx.x;
    if (t == 0) {
        float g[25]; float s = 0.f;
        for (int i = 0; i < 5; i++) for (int j = 0; j < 5; j++) {
            float yy = (float)(i - 2), xx = (float)(j - 2);
            float v = expf(-(xx*xx + yy*yy) * 0.25f);
            g[i*5+j] = v; s += v;
        }
        for (int i = 0; i < 25; i++) { g[i] /= s; filt[i] = g[i]; }
        for (int k = 0; k < 8; k++) {
            float th = (float)k * 3.14159265358979323846f / 8.f;
            float ct = cosf(th), st = sinf(th);
            float d[25]; float mean = 0.f;
            for (int i = 0; i < 5; i++) for (int j = 0; j < 5; j++) {
                float yy = (float)(i - 2), xx = (float)(j - 2);
                d[i*5+j] = (ct*xx + st*yy) * g[i*5+j];
                mean += d[i*5+j];
            }
            mean *= (1.f/25.f);
            float ss = 0.f;
            for (int i = 0; i < 25; i++) { d[i] -= mean; ss += d[i]*d[i]; }
            ss = sqrtf(ss);
            for (int i = 0; i < 25; i++) filt[(k+1)*25 + i] = d[i] / ss;
        }
    }
    for (int i = t; i < 640; i += 256) linbp[i]  = (i < 576) ? lin_b[i]  : 0.f;
    for (int i = t; i < 128; i += 256) convbp[i] = (i < 64)  ? conv_b[i] : 0.f;
}

// ---------------- weight transpose+cast: dst[n][k] = bf16(src[k][n]), zero-pad n>=Nsrc ----------------
__global__ __launch_bounds__(256)
void wtrans_kernel(const float* __restrict__ src, __hip_bfloat16* __restrict__ dst,
                   int K, int Nsrc) {
    __shared__ float tile[32][33];
    const int n0 = blockIdx.x * 32;
    const int k0 = blockIdx.y * 32;
    const int tx = threadIdx.x, ty = threadIdx.y;
    #pragma unroll
    for (int r = ty; r < 32; r += 8) {
        int k = k0 + r, n = n0 + tx;
        tile[r][tx] = (n < Nsrc) ? src[(long)k * Nsrc + n] : 0.f;
    }
    __syncthreads();
    #pragma unroll
    for (int r = ty; r < 32; r += 8) {
        int n = n0 + r, k = k0 + tx;
        dst[(long)n * K + k] = __float2bfloat16(tile[tx][r]);
    }
}

__global__ void wcast_kernel(const float* __restrict__ src, __hip_bfloat16* __restrict__ dst,
                             int count, int total) {
    int i = blockIdx.x * 256 + threadIdx.x;
    if (i < total) dst[i] = __float2bfloat16(i < count ? src[i] : 0.f);
}

// ---- prep: relu + 9-band NSCT conv + concat -> x3 bf16 AND fused LN1(layer0) -> bufA bf16 ----
__global__ __launch_bounds__(256)
void prep_kernel(const float* __restrict__ x, const float* __restrict__ filt,
                 __hip_bfloat16* __restrict__ x3, const float* __restrict__ g1,
                 const float* __restrict__ b1, __hip_bfloat16* __restrict__ lnout) {
    __shared__ float sf[225];
    for (int i = threadIdx.x; i < 225; i += 256) sf[i] = filt[i];
    __syncthreads();
    int id = blockIdx.x * 256 + threadIdx.x;   // B*H*W*C
    int c = id & 63;
    int pix = id >> 6;
    int w = pix % 56, h = (pix / 56) % 56, b = pix / 3136;
    const float* xp = x + (long)(b * 64 + c) * 3136;
    float nb[25];
    #pragma unroll
    for (int dy = 0; dy < 5; dy++) {
        int hy = h + dy - 2;
        #pragma unroll
        for (int dx = 0; dx < 5; dx++) {
            int wx = w + dx - 2;
            float v = 0.f;
            if (hy >= 0 && hy < 56 && wx >= 0 && wx < 56) v = fmaxf(xp[hy*56 + wx], 0.f);
            nb[dy*5 + dx] = v;
        }
    }
    float bo[9];
    __hip_bfloat16* orow = x3 + (long)pix * DD;
    float s = 0.f, s2 = 0.f;
    #pragma unroll
    for (int band = 0; band < 9; band++) {
        float a = 0.f;
        #pragma unroll
        for (int t = 0; t < 25; t++) a += nb[t] * sf[band*25 + t];
        bo[band] = a;
        orow[band*64 + c] = __float2bfloat16(a);
        s += a; s2 += a * a;
    }
    const float ctr = nb[12];
    orow[576 + c] = __float2bfloat16(ctr);     // relu(x) center copy
    s += ctr; s2 += ctr * ctr;
    // wave-wide LN (this wave == this pixel's 64 channels x 10 vals)
    #pragma unroll
    for (int o = 32; o > 0; o >>= 1) { s += __shfl_xor(s, o); s2 += __shfl_xor(s2, o); }
    const float mean = s * (1.f/640.f);
    const float var  = s2 * (1.f/640.f) - mean * mean;
    const float inv  = 1.f / sqrtf(var + 1e-5f);
    __hip_bfloat16* ob = lnout + (long)pix * DD;
    #pragma unroll
    for (int band = 0; band < 9; band++) {
        int ci = band*64 + c;
        ob[ci] = __float2bfloat16((bo[band] - mean) * inv * g1[ci] + b1[ci]);
    }
    ob[576 + c] = __float2bfloat16((ctr - mean) * inv * g1[576 + c] + b1[576 + c]);
}

// ---------------- LayerNorm (per-token over 640, bf16 in) -> bf16 ----------------
__global__ __launch_bounds__(256)
void ln_kernel(const __hip_bfloat16* __restrict__ xin, const float* __restrict__ g,
               const float* __restrict__ bt, __hip_bfloat16* __restrict__ out) {
    const int lane = threadIdx.x & 63;
    const long tok = (long)blockIdx.x * 4 + (threadIdx.x >> 6);
    const __hip_bfloat16* xr = xin + tok * DD;
    float v[10]; float s = 0.f, s2 = 0.f;
    #pragma unroll
    for (int i = 0; i < 10; i++) {
        float t = __bfloat162float(xr[lane + (i << 6)]);
        v[i] = t; s += t; s2 += t*t;
    }
    #pragma unroll
    for (int o = 32; o > 0; o >>= 1) { s += __shfl_xor(s, o); s2 += __shfl_xor(s2, o); }
    const float mean = s * (1.f/640.f);
    const float var  = s2 * (1.f/640.f) - mean * mean;
    const float inv  = 1.f / sqrtf(var + 1e-5f);
    __hip_bfloat16* orow = out + tok * DD;
    #pragma unroll
    for (int i = 0; i < 10; i++) {
        int c = lane + (i << 6);
        orow[c] = __float2bfloat16((v[i] - mean) * inv * g[c] + bt[c]);
    }
}

// ===== 128x128 GEMM, BK=32, double-buffer 32KB, 4 blocks/CU, K-loop unrolled x2 =====
// C = A @ Bt^T + bias [+gelu] [+bf16 resid]; bf16 out (mode 0) or fp32 NCHW scatter (mode 1).
// __launch_bounds__(256,3): reg budget 170, no spill (R11 lesson); runtime occupancy 4 blk/CU
// (128-reg granule caps at 4 waves/SIMD). Swizzle: 16B slot ^= (row>>1)&3 on global source
// + LDS read (rule #21, 0 conflicts). One vmcnt(0)+barrier per K-tile; STAGE(t+1) overlaps.
__global__ __launch_bounds__(256, 3)
void gemm128_kernel(const __hip_bfloat16* __restrict__ A,
                    const __hip_bfloat16* __restrict__ Bt,
                    const float* __restrict__ bias,
                    const __hip_bfloat16* __restrict__ resid,
                    float* __restrict__ Cf,
                    __hip_bfloat16* __restrict__ Cb,
                    int K, int ldb, int col_off, int ncb,
                    int act_gelu, int nvalid, int mode) {
    extern __shared__ __align__(16) char smraw[];   // 2 x 16384B: [A 8192 | B 8192]

    const int tid  = threadIdx.x;
    const int lane = tid & 63;
    const int wv   = tid >> 6;
    const int wr   = wv >> 1;          // 0..1  (M half: 64 rows)
    const int wc   = wv & 1;           // 0..1  (N half: 64 cols)

    // ---- bijective XCD-aware block remap (m204) ----
    const int gx   = gridDim.x;
    const int nwg  = gx * gridDim.y;
    const int orig = blockIdx.y * gx + blockIdx.x;
    const int qq = nwg >> 3, rr = nwg & 7;
    const int xcd = orig & 7, lid = orig >> 3;
    const int wg = (xcd < rr ? xcd * (qq + 1) : rr * (qq + 1) + (xcd - rr) * qq) + lid;
    const long m0 = (long)(wg / gx) * 128;
    const long n0 = (long)(wg % gx) * 128;

    const bool wact = ((int)n0 + (wc << 6)) < nvalid;

    f32x4 acc[4][4];
    #pragma unroll
    for (int i = 0; i < 4; i++)
        #pragma unroll
        for (int j = 0; j < 4; j++) acc[i][j] = (f32x4){0.f, 0.f, 0.f, 0.f};

    // staging: per K-tile(32) each matrix tile is 8KB = 2 x (256 thr x 16B)
    const int r0  = tid >> 2;
    const int sl  = tid & 3;
    const int ssl = sl ^ ((r0 >> 1) & 3);
    const __hip_bfloat16* Agb = A  + (m0 + r0) * (long)K + (ssl << 3);
    const __hip_bfloat16* Bgb = Bt + (n0 + r0) * (long)K + (ssl << 3);
    char* dA = smraw + r0 * 64 + sl * 16;            // linear LDS dest
    char* dB = dA + 8192;

    const int frow = lane & 15;
    const int fks  = lane >> 4;                      // 0..3 (k-slot within K=32)
    const int colA = (fks ^ ((frow >> 1) & 3)) << 4; // swizzled 16B slot -> byte offset

    auto STAGE = [&](int boff, int kt) {
        const long ko = (long)kt << 5;
        gload_lds16(Agb + ko,                dA + boff);
        gload_lds16(Agb + 64 * (long)K + ko, dA + boff + 4096);
        gload_lds16(Bgb + ko,                dB + boff);
        gload_lds16(Bgb + 64 * (long)K + ko, dB + boff + 4096);
    };

#define COMPUTE(BUFOFF)                                                                     \
    do {                                                                                    \
        if (wact) {                                                                         \
            const char* pA = smraw + (BUFOFF);                                              \
            const char* pB = pA + 8192;                                                     \
            short8 af[4], bfr[4];                                                           \
            _Pragma("unroll")                                                               \
            for (int mi = 0; mi < 4; ++mi)                                                  \
                af[mi] = *(const short8*)(pA + ((wr << 6) + (mi << 4) + frow) * 64 + colA); \
            _Pragma("unroll")                                                               \
            for (int nj = 0; nj < 4; ++nj)                                                  \
                bfr[nj] = *(const short8*)(pB + ((wc << 6) + (nj << 4) + frow) * 64 + colA);\
            __builtin_amdgcn_s_setprio(1);                                                  \
            _Pragma("unroll")                                                               \
            for (int mi = 0; mi < 4; ++mi)                                                  \
                _Pragma("unroll")                                                           \
                for (int nj = 0; nj < 4; ++nj)  /* SWAPPED: D rows <- N, cols <- M */       \
                    acc[mi][nj] = __builtin_amdgcn_mfma_f32_16x16x32_bf16(                  \
                        bfr[nj], af[mi], acc[mi][nj], 0, 0, 0);                             \
            __builtin_amdgcn_s_setprio(0);                                                  \
        }                                                                                   \
    } while (0)

    const int nt = K >> 5;                           // EVEN at all call sites (20, 80)
    STAGE(0, 0);
    for (int t = 0; t < nt; t += 2) {
        asm volatile("s_waitcnt vmcnt(0)" ::: "memory");   // tile t landed (own loads)
        __builtin_amdgcn_s_barrier();
        __builtin_amdgcn_sched_barrier(0);
        if (t + 1 < nt) STAGE(16384, t + 1);
        COMPUTE(0);
        asm volatile("s_waitcnt vmcnt(0)" ::: "memory");   // tile t+1 landed
        __builtin_amdgcn_s_barrier();
        __builtin_amdgcn_sched_barrier(0);
        if (t + 2 < nt) STAGE(0, t + 2);
        COMPUTE(16384);
    }
#undef COMPUTE

    if (!wact) return;
    // epilogue: lane holds m = frow (fixed), n = base + fks*4 + r  (4 consecutive cols)
    #pragma unroll
    for (int mi = 0; mi < 4; ++mi) {
        const long row = m0 + (wr << 6) + (mi << 4) + frow;
        #pragma unroll
        for (int nj = 0; nj < 4; ++nj) {
            const int n = (int)n0 + (wc << 6) + (nj << 4) + (fks << 2);
            if (n >= ncb) continue;
            f32x4 v = acc[mi][nj];
            if (bias) {
                const f32x4 bv = *(const f32x4*)&bias[n];
                v += bv;
            }
            if (act_gelu) {
                v[0] = gelu_f(v[0]); v[1] = gelu_f(v[1]); v[2] = gelu_f(v[2]); v[3] = gelu_f(v[3]);
            }
            if (mode == 1) {
                // NCHW scatter: out[(b*64 + n+r)*3136 + pos], row = b*3136 + pos
                const int b = (int)(row / 3136), pos = (int)(row % 3136);
                #pragma unroll
                for (int r = 0; r < 4; ++r)
                    Cf[(long)(b * 64 + n + r) * 3136 + pos] = v[r];
                continue;
            }
            const long base = row * (long)ldb + col_off + n;
            if (resid) {
                const short4 rv = *(const short4*)&resid[base];
                v[0] += bf2f(rv.x); v[1] += bf2f(rv.y);
                v[2] += bf2f(rv.z); v[3] += bf2f(rv.w);
            }
            short4 p;
            p.x = f2bf(v[0]); p.y = f2bf(v[1]); p.z = f2bf(v[2]); p.w = f2bf(v[3]);
            *(short4*)&Cb[base] = p;
        }
    }
}

// ---------------- window attention (per window-head, fp32 in LDS) ----------------
__global__ __launch_bounds__(256)
void attn_kernel(const __hip_bfloat16* __restrict__ qkv, __hip_bfloat16* __restrict__ o,
                 int shift) {
    __shared__ __align__(16) float qT[80][52];
    __shared__ __align__(16) float kT[80][52];
    __shared__ __align__(16) float vs[50][80];
    __shared__ __align__(16) float ss[49][52];
    __shared__ int toks[49];
    __shared__ int rid[49];

    const int tid = threadIdx.x;
    const int win = blockIdx.x >> 3;
    const int hd  = blockIdx.x & 7;
    const int b   = win >> 6;
    const int wh  = (win >> 3) & 7;
    const int ww  = win & 7;

    if (tid < 49) {
        int i = tid / 7, j = tid % 7;
        int ph = wh * 7 + i, pw = ww * 7 + j;
        int sh = ph + shift; if (sh >= 56) sh -= 56;
        int sw = pw + shift; if (sw >= 56) sw -= 56;
        toks[tid] = (b * 56 + sh) * 56 + sw;
        int rh = (ph < 49) ? 0 : ((ph < 53) ? 1 : 2);
        int rw = (pw < 49) ? 0 : ((pw < 53) ? 1 : 2);
        rid[tid] = rh * 3 + rw;
    }
    for (int i = tid; i < 80 * 3; i += 256) {
        int d = i / 3, cc = 49 + (i % 3);
        qT[d][cc] = 0.f; kT[d][cc] = 0.f;
    }
    __syncthreads();
    for (int idx = tid; idx < 49 * 80; idx += 256) {
        int t = idx / 80, d = idx % 80;
        long base = (long)toks[t] * 1920 + hd * 80 + d;
        qT[d][t] = __bfloat162float(qkv[base]);
        kT[d][t] = __bfloat162float(qkv[base + 640]);
        vs[t][d] = __bfloat162float(qkv[base + 1280]);
    }
    __syncthreads();
    const float scale = 0.11180339887498948f;
    for (int p = tid; p < 49 * 13; p += 256) {
        int t = p / 13, j0 = (p % 13) * 4;
        float4 a = {0.f, 0.f, 0.f, 0.f};
        #pragma unroll
        for (int d = 0; d < 80; d++) {
            float qv = qT[d][t];
            float4 kv = *(const float4*)&kT[d][j0];
            a.x += qv * kv.x; a.y += qv * kv.y; a.z += qv * kv.z; a.w += qv * kv.w;
        }
        a.x *= scale; a.y *= scale; a.z *= scale; a.w *= scale;
        *(float4*)&ss[t][j0] = a;
    }
    __syncthreads();
    // parallel softmax: 4 lanes per row (196 threads), shfl_xor reduce within 4-lane group
    if (tid < 196) {
        const int r = tid >> 2, sub = tid & 3;
        const int j0 = sub * 13;
        const int j1 = (sub == 3) ? 10 : 13;
        const int myr = rid[r];
        float mx = -1e30f;
        for (int i = 0; i < j1; i++) {
            float v = ss[r][j0 + i];
            if (shift && rid[j0 + i] != myr) v = -1e9f;
            ss[r][j0 + i] = v;
            mx = fmaxf(mx, v);
        }
        mx = fmaxf(mx, __shfl_xor(mx, 1));
        mx = fmaxf(mx, __shfl_xor(mx, 2));
        float sum = 0.f;
        for (int i = 0; i < j1; i++) {
            float e = __expf(ss[r][j0 + i] - mx);
            ss[r][j0 + i] = e;
            sum += e;
        }
        sum += __shfl_xor(sum, 1);
        sum += __shfl_xor(sum, 2);
        const float inv = 1.f / sum;
        for (int i = 0; i < j1; i++) ss[r][j0 + i] *= inv;
    }
    __syncthreads();
    for (int p = tid; p < 49 * 20; p += 256) {
        int t = p / 20, dv = (p % 20) * 4;
        float4 a = {0.f, 0.f, 0.f, 0.f};
        for (int j = 0; j < 49; j++) {
            float w = ss[t][j];
            float4 vv = *(const float4*)&vs[j][dv];
            a.x += w * vv.x; a.y += w * vv.y; a.z += w * vv.z; a.w += w * vv.w;
        }
        long base = (long)toks[t] * DD + hd * 80 + dv;
        o[base + 0] = __float2bfloat16(a.x);
        o[base + 1] = __float2bfloat16(a.y);
        o[base + 2] = __float2bfloat16(a.z);
        o[base + 3] = __float2bfloat16(a.w);
    }
}

// ---- inverse NSCT: reads bf16 y-mirror (ayc cols [64,640)), writes ayc cols [0,64) ----
__global__ __launch_bounds__(256)
void ict_kernel(__hip_bfloat16* ayc, const float* __restrict__ filt) {
    __shared__ float sf[225];
    for (int i = threadIdx.x; i < 225; i += 256) sf[i] = filt[i];
    __syncthreads();
    int id = blockIdx.x * 256 + threadIdx.x;   // NTOK * 16
    int c4 = (id & 15) << 2;
    int pix = id >> 4;
    int w = pix % 56, h = (pix / 56) % 56, b = pix / 3136;
    float4 a = {0.f, 0.f, 0.f, 0.f};
    #pragma unroll
    for (int dy = 0; dy < 5; dy++) {
        int hy = h + dy - 2;
        if (hy < 0 || hy >= 56) continue;
        #pragma unroll
        for (int dx = 0; dx < 5; dx++) {
            int wx = w + dx - 2;
            if (wx < 0 || wx >= 56) continue;
            const __hip_bfloat16* yr = ayc + ((long)(b * 56 + hy) * 56 + wx) * DD + 64 + c4;
            #pragma unroll
            for (int band = 0; band < 9; band++) {
                const float f = sf[band*25 + dy*5 + dx];
                const short4 sv = *(const short4*)&yr[band * 64];
                a.x += bf2f(sv.x) * f; a.y += bf2f(sv.y) * f;
                a.z += bf2f(sv.z) * f; a.w += bf2f(sv.w) * f;
            }
        }
    }
    short4 p;
    p.x = f2bf(a.x); p.y = f2bf(a.y); p.z = f2bf(a.z); p.w = f2bf(a.w);
    *(short4*)&ayc[(long)pix * DD + c4] = p;
}

// ---------------- host ----------------
extern "C" void kernel_launch(void* const* d_in, const int* in_sizes, int n_in,
                              void* d_out, int out_size, void* d_ws, size_t ws_size,
                              hipStream_t stream) {
    (void)in_sizes; (void)n_in; (void)out_size; (void)ws_size;
    const float* x      = (const float*)d_in[0];
    const float* ln1_g  = (const float*)d_in[1];
    const float* ln1_b  = (const float*)d_in[2];
    const float* qkv_w  = (const float*)d_in[3];
    const float* qkv_b  = (const float*)d_in[4];
    const float* proj_w = (const float*)d_in[5];
    const float* proj_b = (const float*)d_in[6];
    const float* ln2_g  = (const float*)d_in[7];
    const float* ln2_b  = (const float*)d_in[8];
    const float* fc1_w  = (const float*)d_in[9];
    const float* fc1_b  = (const float*)d_in[10];
    const float* fc2_w  = (const float*)d_in[11];
    const float* fc2_b  = (const float*)d_in[12];
    const float* lin_w  = (const float*)d_in[13];
    const float* lin_b  = (const float*)d_in[14];
    const float* conv_w = (const float*)d_in[15];
    const float* conv_b = (const float*)d_in[16];

    char* ws = (char*)d_ws;
    size_t off = 0;
    auto alloc = [&](size_t bytes) -> void* {
        void* p = ws + off;
        off += (bytes + 255) & ~(size_t)255;
        return p;
    };
    float* filt   = (float*)alloc(225 * 4);
    float* linbp  = (float*)alloc(640 * 4);
    float* convbp = (float*)alloc(128 * 4);
    __hip_bfloat16* qkvWt[2], *projWt[2], *fc1Wt[2], *fc2Wt[2];
    for (int i = 0; i < 2; i++) qkvWt[i] = (__hip_bfloat16*)alloc(1920L * 640 * 2);
    for (int i = 0; i < 2; i++) projWt[i] = (__hip_bfloat16*)alloc(640L * 640 * 2);
    for (int i = 0; i < 2; i++) fc1Wt[i] = (__hip_bfloat16*)alloc(2560L * 640 * 2);
    for (int i = 0; i < 2; i++) fc2Wt[i] = (__hip_bfloat16*)alloc(640L * 2560 * 2);
    __hip_bfloat16* linWt  = (__hip_bfloat16*)alloc(640L * 640 * 2);   // N padded 576->640
    __hip_bfloat16* convWt = (__hip_bfloat16*)alloc(128L * 640 * 2);   // N padded 64->128
    __hip_bfloat16* x3   = (__hip_bfloat16*)alloc((long)NTOK * DD * 2);  // bf16 residual stream
    __hip_bfloat16* bufA = (__hip_bfloat16*)alloc((long)NTOK * DD * 2);
    char* bufB = (char*)alloc((long)NTOK * 2560 * 2);
    __hip_bfloat16* qkv = (__hip_bfloat16*)bufB;
    __hip_bfloat16* h2  = (__hip_bfloat16*)bufB;
    __hip_bfloat16* ayc = (__hip_bfloat16*)(bufB + (long)NTOK * DD * 4);

    hipFuncSetAttribute((const void*)gemm128_kernel,
                        hipFuncAttributeMaxDynamicSharedMemorySize, 32768);

    dim3 tb(32, 8);
    init_consts<<<1, 256, 0, stream>>>(filt, linbp, lin_b, convbp, conv_b);
    for (int i = 0; i < 2; i++) {
        wtrans_kernel<<<dim3(60, 20), tb, 0, stream>>>(qkv_w + (long)i*640*1920, qkvWt[i], 640, 1920);
        wtrans_kernel<<<dim3(20, 20), tb, 0, stream>>>(proj_w + (long)i*640*640,  projWt[i], 640, 640);
        wtrans_kernel<<<dim3(80, 20), tb, 0, stream>>>(fc1_w + (long)i*640*2560, fc1Wt[i], 640, 2560);
        wtrans_kernel<<<dim3(20, 80), tb, 0, stream>>>(fc2_w + (long)i*2560*640, fc2Wt[i], 2560, 640);
    }
    wtrans_kernel<<<dim3(20, 20), tb, 0, stream>>>(lin_w, linWt, 640, 576);
    wcast_kernel<<<320, 256, 0, stream>>>(conv_w, convWt, 64 * 640, 128 * 640);

    // prep: writes x3 bf16 + fused LN1(layer0) bf16 into bufA
    prep_kernel<<<6272, 256, 0, stream>>>(x, filt, x3, ln1_g, ln1_b, bufA);

    for (int i = 0; i < 2; i++) {
        int shift = i ? 3 : 0;
        if (i == 1)   // layer 0's LN1 is fused into prep
            ln_kernel<<<6272, 256, 0, stream>>>(x3, ln1_g + i*640, ln1_b + i*640, bufA);
        // qkv: N=1920 exact (15 col-tiles), bf16 out
        gemm128_kernel<<<dim3(15, 196), 256, 32768, stream>>>(bufA, qkvWt[i], qkv_b + i*1920,
            nullptr, nullptr, qkv, 640, 1920, 0, 1920, 0, 1920, 0);
        attn_kernel<<<4096, 256, 0, stream>>>(qkv, bufA, shift);
        // proj: N=640 exact, resid+out = x3 (bf16, in-place elementwise)
        gemm128_kernel<<<dim3(5, 196), 256, 32768, stream>>>(bufA, projWt[i], proj_b + i*640,
            x3, nullptr, x3, 640, 640, 0, 640, 0, 640, 0);
        ln_kernel<<<6272, 256, 0, stream>>>(x3, ln2_g + i*640, ln2_b + i*640, bufA);
        // fc1: N=2560 exact, gelu, bf16 out
        gemm128_kernel<<<dim3(20, 196), 256, 32768, stream>>>(bufA, fc1Wt[i], fc1_b + i*2560,
            nullptr, nullptr, h2, 640, 2560, 0, 2560, 1, 2560, 0);
        // fc2: N=640 exact, K=2560, resid+out = x3 (bf16)
        gemm128_kernel<<<dim3(5, 196), 256, 32768, stream>>>(h2, fc2Wt[i], fc2_b + i*640,
            x3, nullptr, x3, 2560, 640, 0, 640, 0, 640, 0);
    }
    // lin: A = x3 (bf16), bf16 out into ayc cols [64,640)
    gemm128_kernel<<<dim3(5, 196), 256, 32768, stream>>>(x3, linWt, linbp,
        nullptr, nullptr, ayc, 640, 640, 64, 576, 0, 576, 0);
    ict_kernel<<<1568, 256, 0, stream>>>(ayc, filt);   // fills ayc cols [0,64)
    // conv: N=128 (64 valid), direct NCHW store into d_out (fuses unpack)
    gemm128_kernel<<<dim3(1, 196), 256, 32768, stream>>>(ayc, convWt, convbp,
        nullptr, (float*)d_out, nullptr, 640, 0, 0, 64, 0, 64, 1);
}